// Round 1
// baseline (509.585 us; speedup 1.0000x reference)
//
#include <hip/hip_runtime.h>
#include <hip/hip_bf16.h>
#include <cstddef>

#define NEG_SCORE -1e9f

typedef __attribute__((ext_vector_type(8))) short short8;
typedef __attribute__((ext_vector_type(4))) float f32x4;
typedef unsigned short __attribute__((may_alias)) ushort_a;

__device__ inline unsigned short f2bf(float f) {
  union { float f; unsigned int u; } v; v.f = f;
  return (unsigned short)((v.u + 0x7FFFu + ((v.u >> 16) & 1u)) >> 16);
}

// ---------------- LayerNorm: fp32 in -> bf16 out (row = 768) ----------------
__global__ __launch_bounds__(256) void ln_kernel(const float* __restrict__ x,
    const float* __restrict__ g, const float* __restrict__ b,
    unsigned short* __restrict__ out)
{
  int row = blockIdx.x, t = threadIdx.x;
  const float* xr = x + (size_t)row * 768;
  float v0 = xr[t], v1 = xr[t + 256], v2 = xr[t + 512];
  float s = v0 + v1 + v2;
  #pragma unroll
  for (int o = 32; o > 0; o >>= 1) s += __shfl_xor(s, o);
  __shared__ float r1[4], r2[4];
  if ((t & 63) == 0) r1[t >> 6] = s;
  __syncthreads();
  float mean = (r1[0] + r1[1] + r1[2] + r1[3]) * (1.0f / 768.0f);
  float d0 = v0 - mean, d1 = v1 - mean, d2 = v2 - mean;
  float q = d0 * d0 + d1 * d1 + d2 * d2;
  #pragma unroll
  for (int o = 32; o > 0; o >>= 1) q += __shfl_xor(q, o);
  if ((t & 63) == 0) r2[t >> 6] = q;
  __syncthreads();
  float var = (r2[0] + r2[1] + r2[2] + r2[3]) * (1.0f / 768.0f);
  float rs = rsqrtf(var + 1e-6f);
  unsigned short* orow = out + (size_t)row * 768;
  orow[t]       = f2bf(g[t]       * d0 * rs + b[t]);
  orow[t + 256] = f2bf(g[t + 256] * d1 * rs + b[t + 256]);
  orow[t + 512] = f2bf(g[t + 512] * d2 * rs + b[t + 512]);
}

// ------------- transpose + fp32->bf16: W[K][N] -> WT[N][K] ------------------
__global__ __launch_bounds__(256) void transpose_kernel(const float* __restrict__ W,
    unsigned short* __restrict__ WT, int K, int N)
{
  __shared__ float tile[32][33];
  int tx = threadIdx.x & 31, ty = threadIdx.x >> 5;
  int k0 = blockIdx.x * 32, n0 = blockIdx.y * 32;
  #pragma unroll
  for (int i = 0; i < 32; i += 8)
    tile[ty + i][tx] = W[(size_t)(k0 + ty + i) * N + n0 + tx];
  __syncthreads();
  #pragma unroll
  for (int i = 0; i < 32; i += 8)
    WT[(size_t)(n0 + ty + i) * K + k0 + tx] = f2bf(tile[tx][ty + i]);
}

// ---------------- bf16 MFMA GEMM: C = A[M,K] * BT[N,K]^T --------------------
enum { EPI_HEADS = 0, EPI_RELU = 1, EPI_RESID = 2 };

template<int EPI>
__global__ __launch_bounds__(256) void gemm_kernel(
    const unsigned short* __restrict__ A, const unsigned short* __restrict__ BT,
    const float* __restrict__ bias, const float* __restrict__ resid,
    void* __restrict__ outp, int M, int N, int K, float scale)
{
  __shared__ unsigned short lds_a[128][32];
  __shared__ unsigned short lds_b[128][32];
  int tid = threadIdx.x;
  int m0 = blockIdx.x * 128, n0 = blockIdx.y * 128;
  int w = tid >> 6, l = tid & 63;
  int wr = w >> 1, wc = w & 1;
  int fr = l & 15, fq = l >> 4;
  int sr = tid >> 2, sc = (tid & 3) * 8;
  f32x4 acc[4][4] = {};
  for (int k0 = 0; k0 < K; k0 += 32) {
    *reinterpret_cast<uint4*>(&lds_a[sr][sc]) =
        *reinterpret_cast<const uint4*>(&A[(size_t)(m0 + sr) * K + k0 + sc]);
    *reinterpret_cast<uint4*>(&lds_a[sr + 64][sc]) =
        *reinterpret_cast<const uint4*>(&A[(size_t)(m0 + sr + 64) * K + k0 + sc]);
    *reinterpret_cast<uint4*>(&lds_b[sr][sc]) =
        *reinterpret_cast<const uint4*>(&BT[(size_t)(n0 + sr) * K + k0 + sc]);
    *reinterpret_cast<uint4*>(&lds_b[sr + 64][sc]) =
        *reinterpret_cast<const uint4*>(&BT[(size_t)(n0 + sr + 64) * K + k0 + sc]);
    __syncthreads();
    short8 afrag[4], bfrag[4];
    #pragma unroll
    for (int i = 0; i < 4; i++)
      afrag[i] = *reinterpret_cast<const short8*>(&lds_a[wr * 64 + i * 16 + fr][fq * 8]);
    #pragma unroll
    for (int j = 0; j < 4; j++)
      bfrag[j] = *reinterpret_cast<const short8*>(&lds_b[wc * 64 + j * 16 + fr][fq * 8]);
    #pragma unroll
    for (int i = 0; i < 4; i++)
      #pragma unroll
      for (int j = 0; j < 4; j++)
        acc[i][j] = __builtin_amdgcn_mfma_f32_16x16x32_bf16(afrag[i], bfrag[j], acc[i][j], 0, 0, 0);
    __syncthreads();
  }
  #pragma unroll
  for (int i = 0; i < 4; i++) {
    #pragma unroll
    for (int j = 0; j < 4; j++) {
      int col = n0 + wc * 64 + j * 16 + fr;
      #pragma unroll
      for (int r = 0; r < 4; r++) {
        int row = m0 + wr * 64 + i * 16 + fq * 4 + r;
        float c = (acc[i][j][r] + bias[col]) * scale;
        if (EPI == EPI_HEADS) {
          int bb = row >> 12, sl = row & 4095, hh = col >> 6, dh = col & 63;
          reinterpret_cast<unsigned short*>(outp)[(((size_t)(bb * 12 + hh)) * 4096 + sl) * 64 + dh] = f2bf(c);
        } else if (EPI == EPI_RELU) {
          c = fmaxf(c, 0.0f);
          reinterpret_cast<unsigned short*>(outp)[(size_t)row * N + col] = f2bf(c);
        } else {
          c += resid[(size_t)row * N + col];
          reinterpret_cast<float*>(outp)[(size_t)row * N + col] = c;
        }
      }
    }
  }
}

// ---------------- attention scores: S[bhn][256][768] fp32 -------------------
__global__ __launch_bounds__(256) void attn_scores_kernel(
    const unsigned short* __restrict__ q, const unsigned short* __restrict__ k,
    const unsigned char* __restrict__ kpm, float* __restrict__ S, int bhn0)
{
  int bhn = bhn0 + blockIdx.x;
  int kc = blockIdx.y;
  int n = bhn & 15, h = (bhn >> 4) % 12, b = bhn / 192;
  __shared__ unsigned short lds_q[256][64];
  __shared__ unsigned short lds_k[64][64];
  int tid = threadIdx.x;
  int lr = tid >> 3, lc = (tid & 7) * 8;
  const unsigned short* qbase = q + ((size_t)(b * 12 + h) * 4096 + n * 256) * 64;
  #pragma unroll
  for (int i = 0; i < 8; i++)
    *reinterpret_cast<uint4*>(&lds_q[lr + i * 32][lc]) =
        *reinterpret_cast<const uint4*>(&qbase[(size_t)(lr + i * 32) * 64 + lc]);
  int kj0 = kc * 64;
  int g0 = (n - 1) * 256 + kj0;
  bool valid = (g0 >= 0) && (g0 < 4096);
  if (valid) {
    const unsigned short* kbase = k + ((size_t)(b * 12 + h) * 4096 + g0) * 64;
    #pragma unroll
    for (int i = 0; i < 2; i++)
      *reinterpret_cast<uint4*>(&lds_k[lr + i * 32][lc]) =
          *reinterpret_cast<const uint4*>(&kbase[(size_t)(lr + i * 32) * 64 + lc]);
  }
  __syncthreads();
  float* Sblk = S + (size_t)blockIdx.x * 256 * 768;
  int w = tid >> 6, l = tid & 63, fr = l & 15, fq = l >> 4;
  if (!valid) {
    #pragma unroll 4
    for (int t = 0; t < 64; t++) {
      int idx = tid + t * 256;
      Sblk[(size_t)(idx >> 6) * 768 + kj0 + (idx & 63)] = NEG_SCORE;
    }
    return;
  }
  f32x4 acc[4][4] = {};
  #pragma unroll
  for (int ks = 0; ks < 2; ks++) {
    short8 afrag[4], bfrag[4];
    #pragma unroll
    for (int i = 0; i < 4; i++)
      afrag[i] = *reinterpret_cast<const short8*>(&lds_q[w * 64 + i * 16 + fr][ks * 32 + fq * 8]);
    #pragma unroll
    for (int j = 0; j < 4; j++)
      bfrag[j] = *reinterpret_cast<const short8*>(&lds_k[j * 16 + fr][ks * 32 + fq * 8]);
    #pragma unroll
    for (int i = 0; i < 4; i++)
      #pragma unroll
      for (int j = 0; j < 4; j++)
        acc[i][j] = __builtin_amdgcn_mfma_f32_16x16x32_bf16(afrag[i], bfrag[j], acc[i][j], 0, 0, 0);
  }
  const unsigned char* kpmb = kpm + (size_t)b * 4096;
  #pragma unroll
  for (int j = 0; j < 4; j++) {
    int kj = kj0 + j * 16 + fr;
    bool kok = (kpmb[g0 + j * 16 + fr] == 0);
    #pragma unroll
    for (int i = 0; i < 4; i++) {
      #pragma unroll
      for (int r = 0; r < 4; r++) {
        int qi = w * 64 + i * 16 + fq * 4 + r;
        int d = kj - 256 - qi;
        bool ok = kok && (d <= 256) && (d >= -256);
        Sblk[(size_t)qi * 768 + kj] = ok ? acc[i][j][r] : NEG_SCORE;
      }
    }
  }
}

// ------------- row softmax over 768, write bf16 P in place ------------------
__global__ __launch_bounds__(256) void softmax_kernel(float* __restrict__ S)
{
  int wid = threadIdx.x >> 6, l = threadIdx.x & 63;
  size_t row = (size_t)blockIdx.x * 4 + wid;
  float* srow = S + row * 768;
  float v[12];
  float m = -3.4e38f;
  #pragma unroll
  for (int j = 0; j < 12; j++) { v[j] = srow[j * 64 + l]; m = fmaxf(m, v[j]); }
  #pragma unroll
  for (int o = 32; o > 0; o >>= 1) m = fmaxf(m, __shfl_xor(m, o));
  float sum = 0.0f;
  #pragma unroll
  for (int j = 0; j < 12; j++) { v[j] = __expf(v[j] - m); sum += v[j]; }
  #pragma unroll
  for (int o = 32; o > 0; o >>= 1) sum += __shfl_xor(sum, o);
  float inv = 1.0f / sum;
  ushort_a* prow = reinterpret_cast<ushort_a*>(srow);
  #pragma unroll
  for (int j = 0; j < 12; j++) prow[j * 64 + l] = f2bf(v[j] * inv);
}

// ---------------- PV: O[256,64] = P[256,768] @ V3[768,64] -------------------
__global__ __launch_bounds__(256) void attn_pv_kernel(
    const unsigned short* __restrict__ P, const unsigned short* __restrict__ v,
    unsigned short* __restrict__ attn_out, int bhn0)
{
  int bhn = bhn0 + blockIdx.x;
  int n = bhn & 15, h = (bhn >> 4) % 12, b = bhn / 192;
  __shared__ unsigned short lds_p[256][64];
  __shared__ unsigned short lds_vt[64][64];
  int tid = threadIdx.x;
  int w = tid >> 6, l = tid & 63, fr = l & 15, fq = l >> 4;
  int lr = tid >> 3, lc = (tid & 7) * 8;
  const unsigned short* Pbase = P + (size_t)blockIdx.x * 256 * 1536;
  const unsigned short* vbase = v + ((size_t)(b * 12 + h) * 4096) * 64;
  f32x4 acc[4][4] = {};
  for (int kc = 0; kc < 12; kc++) {
    int kj0 = kc * 64;
    int g0 = (n - 1) * 256 + kj0;
    bool valid = (g0 >= 0) && (g0 < 4096);
    if (valid) {
      #pragma unroll
      for (int i = 0; i < 8; i++)
        *reinterpret_cast<uint4*>(&lds_p[lr + i * 32][lc]) =
            *reinterpret_cast<const uint4*>(&Pbase[(size_t)(lr + i * 32) * 1536 + kj0 + lc]);
      #pragma unroll
      for (int i = 0; i < 2; i++) {
        uint4 raw = *reinterpret_cast<const uint4*>(&vbase[(size_t)(g0 + lr + i * 32) * 64 + lc]);
        const unsigned short* pr = reinterpret_cast<const unsigned short*>(&raw);
        #pragma unroll
        for (int e = 0; e < 8; e++) lds_vt[lc + e][lr + i * 32] = pr[e];
      }
    }
    __syncthreads();
    if (valid) {
      #pragma unroll
      for (int ks = 0; ks < 2; ks++) {
        short8 afrag[4], bfrag[4];
        #pragma unroll
        for (int i = 0; i < 4; i++)
          afrag[i] = *reinterpret_cast<const short8*>(&lds_p[w * 64 + i * 16 + fr][ks * 32 + fq * 8]);
        #pragma unroll
        for (int j = 0; j < 4; j++)
          bfrag[j] = *reinterpret_cast<const short8*>(&lds_vt[j * 16 + fr][ks * 32 + fq * 8]);
        #pragma unroll
        for (int i = 0; i < 4; i++)
          #pragma unroll
          for (int j = 0; j < 4; j++)
            acc[i][j] = __builtin_amdgcn_mfma_f32_16x16x32_bf16(afrag[i], bfrag[j], acc[i][j], 0, 0, 0);
      }
    }
    __syncthreads();
  }
  #pragma unroll
  for (int i = 0; i < 4; i++)
    #pragma unroll
    for (int j = 0; j < 4; j++)
      #pragma unroll
      for (int r = 0; r < 4; r++) {
        int qi = w * 64 + i * 16 + fq * 4 + r;
        int dd = j * 16 + fr;
        size_t srow = (size_t)b * 4096 + n * 256 + qi;
        attn_out[srow * 768 + h * 64 + dd] = f2bf(acc[i][j][r]);
      }
}

extern "C" void kernel_launch(void* const* d_in, const int* in_sizes, int n_in,
                              void* d_out, int out_size, void* d_ws, size_t ws_size,
                              hipStream_t stream) {
  const float* x            = (const float*)d_in[0];
  const unsigned char* mask = (const unsigned char*)d_in[1];
  const float* Wq  = (const float*)d_in[3];
  const float* bq  = (const float*)d_in[4];
  const float* Wk  = (const float*)d_in[5];
  const float* bk  = (const float*)d_in[6];
  const float* Wv  = (const float*)d_in[7];
  const float* bv  = (const float*)d_in[8];
  const float* Wo  = (const float*)d_in[9];
  const float* bo  = (const float*)d_in[10];
  const float* ln1g = (const float*)d_in[11];
  const float* ln1b = (const float*)d_in[12];
  const float* W1  = (const float*)d_in[13];
  const float* b1  = (const float*)d_in[14];
  const float* W2  = (const float*)d_in[15];
  const float* b2  = (const float*)d_in[16];
  const float* ln2g = (const float*)d_in[17];
  const float* ln2b = (const float*)d_in[18];
  float* out = (float*)d_out;

  char* ws = (char*)d_ws;
  size_t off = 0;
  auto alloc = [&](size_t bytes) -> void* {
    void* p = ws + off;
    off += (bytes + 255) & ~(size_t)255;
    return p;
  };
  unsigned short* WTq = (unsigned short*)alloc(768u * 768u * 2u);
  unsigned short* WTk = (unsigned short*)alloc(768u * 768u * 2u);
  unsigned short* WTv = (unsigned short*)alloc(768u * 768u * 2u);
  unsigned short* WTo = (unsigned short*)alloc(768u * 768u * 2u);
  unsigned short* W1T = (unsigned short*)alloc((size_t)3072 * 768 * 2);
  unsigned short* W2T = (unsigned short*)alloc((size_t)768 * 3072 * 2);
  unsigned short* hbuf = (unsigned short*)alloc((size_t)8192 * 768 * 2);
  unsigned short* qb   = (unsigned short*)alloc((size_t)8192 * 768 * 2);
  unsigned short* kb   = (unsigned short*)alloc((size_t)8192 * 768 * 2);
  unsigned short* vb   = (unsigned short*)alloc((size_t)8192 * 768 * 2);
  unsigned short* attn = (unsigned short*)alloc((size_t)8192 * 768 * 2);
  float* x1 = (float*)alloc((size_t)8192 * 768 * 4);
  unsigned short* h2 = (unsigned short*)alloc((size_t)8192 * 768 * 2);
  unsigned short* a1 = (unsigned short*)alloc((size_t)8192 * 3072 * 2);
  float* Sbuf = (float*)(ws + off);
  size_t sbytes = (ws_size > off) ? (ws_size - off) : 0;
  size_t per_bhn = (size_t)256 * 768 * 4;
  int max_chunk = (int)(sbytes / per_bhn);
  if (max_chunk > 384) max_chunk = 384;
  if (max_chunk < 1) return;  // workspace too small

  transpose_kernel<<<dim3(24, 24), 256, 0, stream>>>(Wq, WTq, 768, 768);
  transpose_kernel<<<dim3(24, 24), 256, 0, stream>>>(Wk, WTk, 768, 768);
  transpose_kernel<<<dim3(24, 24), 256, 0, stream>>>(Wv, WTv, 768, 768);
  transpose_kernel<<<dim3(24, 24), 256, 0, stream>>>(Wo, WTo, 768, 768);
  transpose_kernel<<<dim3(24, 96), 256, 0, stream>>>(W1, W1T, 768, 3072);
  transpose_kernel<<<dim3(96, 24), 256, 0, stream>>>(W2, W2T, 3072, 768);

  ln_kernel<<<8192, 256, 0, stream>>>(x, ln1g, ln1b, hbuf);

  gemm_kernel<EPI_HEADS><<<dim3(64, 6), 256, 0, stream>>>(hbuf, WTq, bq, nullptr, qb, 8192, 768, 768, 0.125f);
  gemm_kernel<EPI_HEADS><<<dim3(64, 6), 256, 0, stream>>>(hbuf, WTk, bk, nullptr, kb, 8192, 768, 768, 1.0f);
  gemm_kernel<EPI_HEADS><<<dim3(64, 6), 256, 0, stream>>>(hbuf, WTv, bv, nullptr, vb, 8192, 768, 768, 1.0f);

  for (int c0 = 0; c0 < 384; c0 += max_chunk) {
    int cc = (384 - c0 < max_chunk) ? (384 - c0) : max_chunk;
    attn_scores_kernel<<<dim3(cc, 12), 256, 0, stream>>>(qb, kb, mask, Sbuf, c0);
    softmax_kernel<<<cc * 64, 256, 0, stream>>>(Sbuf);
    attn_pv_kernel<<<cc, 256, 0, stream>>>((const unsigned short*)Sbuf, vb, attn, c0);
  }

  gemm_kernel<EPI_RESID><<<dim3(64, 6), 256, 0, stream>>>(attn, WTo, bo, x, x1, 8192, 768, 768, 1.0f);
  ln_kernel<<<8192, 256, 0, stream>>>(x1, ln2g, ln2b, h2);
  gemm_kernel<EPI_RELU><<<dim3(64, 24), 256, 0, stream>>>(h2, W1T, b1, nullptr, a1, 8192, 3072, 768, 1.0f);
  gemm_kernel<EPI_RESID><<<dim3(64, 6), 256, 0, stream>>>(a1, W2T, b2, x1, out, 8192, 768, 3072, 1.0f);
}

// Round 2
// 367.839 us; speedup vs baseline: 1.3853x; 1.3853x over previous
//
#include <hip/hip_runtime.h>
#include <hip/hip_bf16.h>
#include <cstddef>

typedef __attribute__((ext_vector_type(8))) short short8;
typedef __attribute__((ext_vector_type(4))) float f32x4;

typedef __attribute__((address_space(1))) void as1_void;
typedef __attribute__((address_space(3))) void as3_void;

__device__ __forceinline__ void gload16(const void* g, void* lds) {
  __builtin_amdgcn_global_load_lds((as1_void*)(void*)g, (as3_void*)lds, 16, 0, 0);
}

__device__ inline unsigned short f2bf(float f) {
  union { float f; unsigned int u; } v; v.f = f;
  return (unsigned short)((v.u + 0x7FFFu + ((v.u >> 16) & 1u)) >> 16);
}

// ---------------- LayerNorm: fp32 in -> bf16 out (row = 768) ----------------
__global__ __launch_bounds__(256) void ln_kernel(const float* __restrict__ x,
    const float* __restrict__ g, const float* __restrict__ b,
    unsigned short* __restrict__ out)
{
  int row = blockIdx.x, t = threadIdx.x;
  const float* xr = x + (size_t)row * 768;
  float v0 = xr[t], v1 = xr[t + 256], v2 = xr[t + 512];
  float s = v0 + v1 + v2;
  #pragma unroll
  for (int o = 32; o > 0; o >>= 1) s += __shfl_xor(s, o);
  __shared__ float r1[4], r2[4];
  if ((t & 63) == 0) r1[t >> 6] = s;
  __syncthreads();
  float mean = (r1[0] + r1[1] + r1[2] + r1[3]) * (1.0f / 768.0f);
  float d0 = v0 - mean, d1 = v1 - mean, d2 = v2 - mean;
  float q = d0 * d0 + d1 * d1 + d2 * d2;
  #pragma unroll
  for (int o = 32; o > 0; o >>= 1) q += __shfl_xor(q, o);
  if ((t & 63) == 0) r2[t >> 6] = q;
  __syncthreads();
  float var = (r2[0] + r2[1] + r2[2] + r2[3]) * (1.0f / 768.0f);
  float rs = rsqrtf(var + 1e-6f);
  unsigned short* orow = out + (size_t)row * 768;
  orow[t]       = f2bf(g[t]       * d0 * rs + b[t]);
  orow[t + 256] = f2bf(g[t + 256] * d1 * rs + b[t + 256]);
  orow[t + 512] = f2bf(g[t + 512] * d2 * rs + b[t + 512]);
}

// ------------- transpose + fp32->bf16: W[K][N] -> WT[N][K] ------------------
__global__ __launch_bounds__(256) void transpose_kernel(const float* __restrict__ W,
    unsigned short* __restrict__ WT, int K, int N)
{
  __shared__ float tile[32][33];
  int tx = threadIdx.x & 31, ty = threadIdx.x >> 5;
  int k0 = blockIdx.x * 32, n0 = blockIdx.y * 32;
  #pragma unroll
  for (int i = 0; i < 32; i += 8)
    tile[ty + i][tx] = W[(size_t)(k0 + ty + i) * N + n0 + tx];
  __syncthreads();
  #pragma unroll
  for (int i = 0; i < 32; i += 8)
    WT[(size_t)(n0 + ty + i) * K + k0 + tx] = f2bf(tile[tx][ty + i]);
}

// ---------------- bf16 MFMA GEMM: C = A[M,K] * BT[N,K]^T --------------------
// 128x128 tile, BK=64, global_load_lds staging w/ pre-swizzled source,
// XOR-swizzled LDS (byte ^= (row&7)<<4) -> conflict-free ds_read_b128.
enum { EPI_HEADS = 0, EPI_RELU = 1, EPI_RESID = 2 };

template<int EPI>
__global__ __launch_bounds__(256) void gemm_kernel(
    const unsigned short* __restrict__ A, const unsigned short* __restrict__ BT,
    const float* __restrict__ bias, const float* __restrict__ resid,
    void* __restrict__ outp, int M, int N, int K, float scale)
{
  __shared__ unsigned short lds_a[128 * 64];
  __shared__ unsigned short lds_b[128 * 64];
  int tid = threadIdx.x;
  int m0 = blockIdx.x * 128, n0 = blockIdx.y * 128;
  int w = tid >> 6, l = tid & 63;
  int wr = w >> 1, wc = w & 1;
  int fr = l & 15, fq = l >> 4;
  int lrow8 = l >> 3;
  int swzb = (((l & 7) ^ lrow8) << 4);
  const char* Ab = (const char*)A;
  const char* Bb = (const char*)BT;
  f32x4 acc[4][4] = {};
  for (int k0 = 0; k0 < K; k0 += 64) {
    #pragma unroll
    for (int s = 0; s < 4; s++) {
      int row = w * 32 + s * 8 + lrow8;
      gload16(Ab + ((size_t)(m0 + row) * K + k0) * 2 + swzb,
              (char*)lds_a + w * 4096 + s * 1024);
      gload16(Bb + ((size_t)(n0 + row) * K + k0) * 2 + swzb,
              (char*)lds_b + w * 4096 + s * 1024);
    }
    __syncthreads();
    #pragma unroll
    for (int ks = 0; ks < 2; ks++) {
      int colb = (ks * 64 + (fq << 4)) ^ ((fr & 7) << 4);
      short8 af[4], bf[4];
      #pragma unroll
      for (int i = 0; i < 4; i++)
        af[i] = *(const short8*)((const char*)lds_a + (wr * 64 + i * 16 + fr) * 128 + colb);
      #pragma unroll
      for (int j = 0; j < 4; j++)
        bf[j] = *(const short8*)((const char*)lds_b + (wc * 64 + j * 16 + fr) * 128 + colb);
      #pragma unroll
      for (int i = 0; i < 4; i++)
        #pragma unroll
        for (int j = 0; j < 4; j++)
          acc[i][j] = __builtin_amdgcn_mfma_f32_16x16x32_bf16(af[i], bf[j], acc[i][j], 0, 0, 0);
    }
    __syncthreads();
  }
  #pragma unroll
  for (int i = 0; i < 4; i++) {
    #pragma unroll
    for (int j = 0; j < 4; j++) {
      int col = n0 + wc * 64 + j * 16 + fr;
      #pragma unroll
      for (int r = 0; r < 4; r++) {
        int row = m0 + wr * 64 + i * 16 + fq * 4 + r;
        float c = (acc[i][j][r] + bias[col]) * scale;
        if (EPI == EPI_HEADS) {
          int bb = row >> 12, sl = row & 4095, hh = col >> 6, dh = col & 63;
          reinterpret_cast<unsigned short*>(outp)[(((size_t)(bb * 12 + hh)) * 4096 + sl) * 64 + dh] = f2bf(c);
        } else if (EPI == EPI_RELU) {
          c = fmaxf(c, 0.0f);
          reinterpret_cast<unsigned short*>(outp)[(size_t)row * N + col] = f2bf(c);
        } else {
          c += resid[(size_t)row * N + col];
          reinterpret_cast<float*>(outp)[(size_t)row * N + col] = c;
        }
      }
    }
  }
}

// -------- fused sliding-window attention (flash-style, per (b,h,n)) ---------
// Block = 256 threads = 4 waves; wave w owns q-rows [w*64, w*64+64).
// Online softmax over 12 chunks of 64 keys; P round-trips wave-local LDS.
__global__ __launch_bounds__(256) void attn_fused_kernel(
    const unsigned short* __restrict__ qg, const unsigned short* __restrict__ kg,
    const unsigned short* __restrict__ vg, const unsigned char* __restrict__ kpm,
    unsigned short* __restrict__ attn_out)
{
  __shared__ unsigned short lds_q[256 * 64];     // 32 KB, swizzled
  __shared__ unsigned short lds_k[64 * 64];      // 8 KB, swizzled
  __shared__ unsigned short lds_vt[64 * 64];     // 8 KB, V^T [d][key], swizzled
  __shared__ unsigned short lds_p[4][64 * 64];   // 32 KB, per-wave P tile
  int bhn = blockIdx.x;
  int n = bhn & 15, h = (bhn >> 4) % 12, b = bhn / 192;
  int bh = b * 12 + h;
  int tid = threadIdx.x;
  int w = tid >> 6, l = tid & 63;
  int fr = l & 15, fq = l >> 4;
  int lrow8 = l >> 3;
  int swzb = (((l & 7) ^ lrow8) << 4);
  const char* qbase = (const char*)(qg + ((size_t)bh * 4096 + n * 256) * 64);
  #pragma unroll
  for (int s = 0; s < 8; s++) {
    int row = w * 64 + s * 8 + lrow8;
    gload16(qbase + (size_t)row * 128 + swzb, (char*)lds_q + w * 8192 + s * 1024);
  }
  const char* kbase0 = (const char*)(kg + (size_t)bh * 4096 * 64);
  const unsigned short* vbase = vg + (size_t)bh * 4096 * 64;
  const unsigned char* kpmb = kpm + (size_t)b * 4096;
  int lr = tid >> 3, lc = (tid & 7) * 8;

  f32x4 acc_o[4][4] = {};
  float m_st[4][4], l_st[4][4];
  #pragma unroll
  for (int i = 0; i < 4; i++)
    #pragma unroll
    for (int r = 0; r < 4; r++) { m_st[i][r] = -3.0e38f; l_st[i][r] = 0.0f; }

  for (int kc = 0; kc < 12; kc++) {
    int g0 = (n - 1) * 256 + kc * 64;
    bool valid = (g0 >= 0) && (g0 < 4096);
    if (valid) {
      #pragma unroll
      for (int s = 0; s < 2; s++) {
        int row = w * 16 + s * 8 + lrow8;
        gload16(kbase0 + ((size_t)g0 + row) * 128 + swzb, (char*)lds_k + w * 2048 + s * 1024);
      }
      #pragma unroll
      for (int it = 0; it < 2; it++) {
        int key = lr + it * 32;
        uint4 raw = *reinterpret_cast<const uint4*>(&vbase[((size_t)g0 + key) * 64 + lc]);
        const unsigned short* pr = (const unsigned short*)&raw;
        #pragma unroll
        for (int e = 0; e < 8; e++) {
          int d = lc + e;
          *(unsigned short*)((char*)lds_vt + d * 128 + ((key * 2) ^ ((d & 7) << 4))) = pr[e];
        }
      }
    }
    __syncthreads();
    if (valid) {
      short8 kb[4][2];
      #pragma unroll
      for (int j = 0; j < 4; j++)
        #pragma unroll
        for (int ks = 0; ks < 2; ks++)
          kb[j][ks] = *(const short8*)((const char*)lds_k + (j * 16 + fr) * 128 +
                       ((ks * 64 + (fq << 4)) ^ ((fr & 7) << 4)));
      int kmask[4];
      #pragma unroll
      for (int j = 0; j < 4; j++) kmask[j] = kpmb[g0 + j * 16 + fr];
      #pragma unroll
      for (int i = 0; i < 4; i++) {
        f32x4 accs[4] = {};
        #pragma unroll
        for (int ks = 0; ks < 2; ks++) {
          short8 qa = *(const short8*)((const char*)lds_q + (w * 64 + i * 16 + fr) * 128 +
                       ((ks * 64 + (fq << 4)) ^ ((fr & 7) << 4)));
          #pragma unroll
          for (int j = 0; j < 4; j++)
            accs[j] = __builtin_amdgcn_mfma_f32_16x16x32_bf16(qa, kb[j][ks], accs[j], 0, 0, 0);
        }
        #pragma unroll
        for (int r = 0; r < 4; r++) {
          int qi = w * 64 + i * 16 + fq * 4 + r;   // q within block [0,256)
          float sv[4];
          float mv = -3.0e38f;
          #pragma unroll
          for (int j = 0; j < 4; j++) {
            int dq = g0 + j * 16 + fr - n * 256 - qi;
            bool ok = (kmask[j] == 0) && (dq <= 256) && (dq >= -256);
            float s = ok ? accs[j][r] : -3.0e38f;
            sv[j] = s;
            mv = fmaxf(mv, s);
          }
          #pragma unroll
          for (int o = 1; o <= 8; o <<= 1) mv = fmaxf(mv, __shfl_xor(mv, o));
          float mo = m_st[i][r];
          float mn = fmaxf(mo, mv);
          float scl = __expf(mo - mn);
          float rs = 0.0f;
          unsigned short pb[4];
          #pragma unroll
          for (int j = 0; j < 4; j++) {
            float p = (sv[j] > -1.0e37f) ? __expf(sv[j] - mn) : 0.0f;
            rs += p;
            pb[j] = f2bf(p);
          }
          #pragma unroll
          for (int o = 1; o <= 8; o <<= 1) rs += __shfl_xor(rs, o);
          l_st[i][r] = l_st[i][r] * scl + rs;
          m_st[i][r] = mn;
          #pragma unroll
          for (int j = 0; j < 4; j++) acc_o[i][j][r] *= scl;
          int prow = i * 16 + fq * 4 + r;
          #pragma unroll
          for (int j = 0; j < 4; j++)
            *(unsigned short*)((char*)lds_p[w] + prow * 128 +
                (((j * 16 + fr) * 2) ^ ((prow & 7) << 4))) = pb[j];
        }
      }
      short8 vb[4][2];
      #pragma unroll
      for (int jd = 0; jd < 4; jd++)
        #pragma unroll
        for (int ks = 0; ks < 2; ks++)
          vb[jd][ks] = *(const short8*)((const char*)lds_vt + (jd * 16 + fr) * 128 +
                        ((ks * 64 + (fq << 4)) ^ ((fr & 7) << 4)));
      #pragma unroll
      for (int i = 0; i < 4; i++) {
        #pragma unroll
        for (int ks = 0; ks < 2; ks++) {
          short8 pa = *(const short8*)((const char*)lds_p[w] + (i * 16 + fr) * 128 +
                       ((ks * 64 + (fq << 4)) ^ ((fr & 7) << 4)));
          #pragma unroll
          for (int jd = 0; jd < 4; jd++)
            acc_o[i][jd] = __builtin_amdgcn_mfma_f32_16x16x32_bf16(pa, vb[jd][ks], acc_o[i][jd], 0, 0, 0);
        }
      }
    }
    __syncthreads();
  }
  #pragma unroll
  for (int i = 0; i < 4; i++) {
    #pragma unroll
    for (int r = 0; r < 4; r++) {
      float inv = 1.0f / l_st[i][r];
      size_t srow = (size_t)b * 4096 + n * 256 + w * 64 + i * 16 + fq * 4 + r;
      #pragma unroll
      for (int jd = 0; jd < 4; jd++)
        attn_out[srow * 768 + h * 64 + jd * 16 + fr] = f2bf(acc_o[i][jd][r] * inv);
    }
  }
}

extern "C" void kernel_launch(void* const* d_in, const int* in_sizes, int n_in,
                              void* d_out, int out_size, void* d_ws, size_t ws_size,
                              hipStream_t stream) {
  const float* x            = (const float*)d_in[0];
  const unsigned char* mask = (const unsigned char*)d_in[1];
  const float* Wq  = (const float*)d_in[3];
  const float* bq  = (const float*)d_in[4];
  const float* Wk  = (const float*)d_in[5];
  const float* bk  = (const float*)d_in[6];
  const float* Wv  = (const float*)d_in[7];
  const float* bv  = (const float*)d_in[8];
  const float* Wo  = (const float*)d_in[9];
  const float* bo  = (const float*)d_in[10];
  const float* ln1g = (const float*)d_in[11];
  const float* ln1b = (const float*)d_in[12];
  const float* W1  = (const float*)d_in[13];
  const float* b1  = (const float*)d_in[14];
  const float* W2  = (const float*)d_in[15];
  const float* b2  = (const float*)d_in[16];
  const float* ln2g = (const float*)d_in[17];
  const float* ln2b = (const float*)d_in[18];
  float* out = (float*)d_out;

  char* ws = (char*)d_ws;
  size_t off = 0;
  auto alloc = [&](size_t bytes) -> void* {
    void* p = ws + off;
    off += (bytes + 255) & ~(size_t)255;
    return p;
  };
  unsigned short* WTq = (unsigned short*)alloc(768u * 768u * 2u);
  unsigned short* WTk = (unsigned short*)alloc(768u * 768u * 2u);
  unsigned short* WTv = (unsigned short*)alloc(768u * 768u * 2u);
  unsigned short* WTo = (unsigned short*)alloc(768u * 768u * 2u);
  unsigned short* W1T = (unsigned short*)alloc((size_t)3072 * 768 * 2);
  unsigned short* W2T = (unsigned short*)alloc((size_t)768 * 3072 * 2);
  unsigned short* hbuf = (unsigned short*)alloc((size_t)8192 * 768 * 2);
  unsigned short* qb   = (unsigned short*)alloc((size_t)8192 * 768 * 2);
  unsigned short* kb   = (unsigned short*)alloc((size_t)8192 * 768 * 2);
  unsigned short* vb   = (unsigned short*)alloc((size_t)8192 * 768 * 2);
  unsigned short* attn = (unsigned short*)alloc((size_t)8192 * 768 * 2);
  float* x1 = (float*)alloc((size_t)8192 * 768 * 4);
  unsigned short* h2 = (unsigned short*)alloc((size_t)8192 * 768 * 2);
  unsigned short* a1 = (unsigned short*)alloc((size_t)8192 * 3072 * 2);

  transpose_kernel<<<dim3(24, 24), 256, 0, stream>>>(Wq, WTq, 768, 768);
  transpose_kernel<<<dim3(24, 24), 256, 0, stream>>>(Wk, WTk, 768, 768);
  transpose_kernel<<<dim3(24, 24), 256, 0, stream>>>(Wv, WTv, 768, 768);
  transpose_kernel<<<dim3(24, 24), 256, 0, stream>>>(Wo, WTo, 768, 768);
  transpose_kernel<<<dim3(24, 96), 256, 0, stream>>>(W1, W1T, 768, 3072);
  transpose_kernel<<<dim3(96, 24), 256, 0, stream>>>(W2, W2T, 3072, 768);

  ln_kernel<<<8192, 256, 0, stream>>>(x, ln1g, ln1b, hbuf);

  gemm_kernel<EPI_HEADS><<<dim3(64, 6), 256, 0, stream>>>(hbuf, WTq, bq, nullptr, qb, 8192, 768, 768, 0.125f);
  gemm_kernel<EPI_HEADS><<<dim3(64, 6), 256, 0, stream>>>(hbuf, WTk, bk, nullptr, kb, 8192, 768, 768, 1.0f);
  gemm_kernel<EPI_HEADS><<<dim3(64, 6), 256, 0, stream>>>(hbuf, WTv, bv, nullptr, vb, 8192, 768, 768, 1.0f);

  attn_fused_kernel<<<384, 256, 0, stream>>>(qb, kb, vb, mask, attn);

  gemm_kernel<EPI_RESID><<<dim3(64, 6), 256, 0, stream>>>(attn, WTo, bo, x, x1, 8192, 768, 768, 1.0f);
  ln_kernel<<<8192, 256, 0, stream>>>(x1, ln2g, ln2b, h2);
  gemm_kernel<EPI_RELU><<<dim3(64, 24), 256, 0, stream>>>(h2, W1T, b1, nullptr, a1, 8192, 3072, 768, 1.0f);
  gemm_kernel<EPI_RESID><<<dim3(64, 6), 256, 0, stream>>>(a1, W2T, b2, x1, out, 8192, 768, 3072, 1.0f);
}

// Round 3
// 288.079 us; speedup vs baseline: 1.7689x; 1.2769x over previous
//
#include <hip/hip_runtime.h>
#include <hip/hip_bf16.h>
#include <cstddef>

typedef __attribute__((ext_vector_type(8))) short short8;
typedef __attribute__((ext_vector_type(4))) float f32x4;

typedef __attribute__((address_space(1))) void as1_void;
typedef __attribute__((address_space(3))) void as3_void;

__device__ __forceinline__ void gload16(const void* g, void* lds) {
  __builtin_amdgcn_global_load_lds((as1_void*)(void*)g, (as3_void*)lds, 16, 0, 0);
}

__device__ inline unsigned short f2bf(float f) {
  union { float f; unsigned int u; } v; v.f = f;
  return (unsigned short)((v.u + 0x7FFFu + ((v.u >> 16) & 1u)) >> 16);
}

// ---------------- LayerNorm: fp32 in -> bf16 out (row = 768) ----------------
__global__ __launch_bounds__(256) void ln_kernel(const float* __restrict__ x,
    const float* __restrict__ g, const float* __restrict__ b,
    unsigned short* __restrict__ out)
{
  int row = blockIdx.x, t = threadIdx.x;
  const float* xr = x + (size_t)row * 768;
  float v0 = xr[t], v1 = xr[t + 256], v2 = xr[t + 512];
  float s = v0 + v1 + v2;
  #pragma unroll
  for (int o = 32; o > 0; o >>= 1) s += __shfl_xor(s, o);
  __shared__ float r1[4], r2[4];
  if ((t & 63) == 0) r1[t >> 6] = s;
  __syncthreads();
  float mean = (r1[0] + r1[1] + r1[2] + r1[3]) * (1.0f / 768.0f);
  float d0 = v0 - mean, d1 = v1 - mean, d2 = v2 - mean;
  float q = d0 * d0 + d1 * d1 + d2 * d2;
  #pragma unroll
  for (int o = 32; o > 0; o >>= 1) q += __shfl_xor(q, o);
  if ((t & 63) == 0) r2[t >> 6] = q;
  __syncthreads();
  float var = (r2[0] + r2[1] + r2[2] + r2[3]) * (1.0f / 768.0f);
  float rs = rsqrtf(var + 1e-6f);
  unsigned short* orow = out + (size_t)row * 768;
  orow[t]       = f2bf(g[t]       * d0 * rs + b[t]);
  orow[t + 256] = f2bf(g[t + 256] * d1 * rs + b[t + 256]);
  orow[t + 512] = f2bf(g[t + 512] * d2 * rs + b[t + 512]);
}

// ------------- transpose + fp32->bf16: W[K][N] -> WT[N][K] ------------------
__global__ __launch_bounds__(256) void transpose_kernel(const float* __restrict__ W,
    unsigned short* __restrict__ WT, int K, int N)
{
  __shared__ float tile[32][33];
  int tx = threadIdx.x & 31, ty = threadIdx.x >> 5;
  int k0 = blockIdx.x * 32, n0 = blockIdx.y * 32;
  #pragma unroll
  for (int i = 0; i < 32; i += 8)
    tile[ty + i][tx] = W[(size_t)(k0 + ty + i) * N + n0 + tx];
  __syncthreads();
  #pragma unroll
  for (int i = 0; i < 32; i += 8)
    WT[(size_t)(n0 + ty + i) * K + k0 + tx] = f2bf(tile[tx][ty + i]);
}

// -------------------- concat bias [bq|bk|bv] -> 2304 ------------------------
__global__ __launch_bounds__(256) void catbias_kernel(const float* __restrict__ bq,
    const float* __restrict__ bk, const float* __restrict__ bv, float* __restrict__ o)
{
  int i = blockIdx.x * 256 + threadIdx.x;
  o[i] = (i < 768) ? bq[i] : ((i < 1536) ? bk[i - 768] : bv[i - 1536]);
}

// ---------------- bf16 MFMA GEMM: C = A[M,K] * BT[N,K]^T --------------------
enum { EPI_QKV = 0, EPI_RELU = 1, EPI_RESID = 2 };

template<int EPI>
__global__ __launch_bounds__(256) void gemm_kernel(
    const unsigned short* __restrict__ A, const unsigned short* __restrict__ BT,
    const float* __restrict__ bias, const float* __restrict__ resid,
    void* __restrict__ outp, int M, int N, int K, float scale)
{
  __shared__ unsigned short lds_a[128 * 64];
  __shared__ unsigned short lds_b[128 * 64];
  int tid = threadIdx.x;
  int m0 = blockIdx.x * 128, n0 = blockIdx.y * 128;
  int w = tid >> 6, l = tid & 63;
  int wr = w >> 1, wc = w & 1;
  int fr = l & 15, fq = l >> 4;
  int lrow8 = l >> 3;
  int swzb = (((l & 7) ^ lrow8) << 4);
  const char* Ab = (const char*)A;
  const char* Bb = (const char*)BT;
  f32x4 acc[4][4] = {};
  for (int k0 = 0; k0 < K; k0 += 64) {
    #pragma unroll
    for (int s = 0; s < 4; s++) {
      int row = w * 32 + s * 8 + lrow8;
      gload16(Ab + ((size_t)(m0 + row) * K + k0) * 2 + swzb,
              (char*)lds_a + w * 4096 + s * 1024);
      gload16(Bb + ((size_t)(n0 + row) * K + k0) * 2 + swzb,
              (char*)lds_b + w * 4096 + s * 1024);
    }
    __syncthreads();
    #pragma unroll
    for (int ks = 0; ks < 2; ks++) {
      int colb = (ks * 64 + (fq << 4)) ^ ((fr & 7) << 4);
      short8 af[4], bf[4];
      #pragma unroll
      for (int i = 0; i < 4; i++)
        af[i] = *(const short8*)((const char*)lds_a + (wr * 64 + i * 16 + fr) * 128 + colb);
      #pragma unroll
      for (int j = 0; j < 4; j++)
        bf[j] = *(const short8*)((const char*)lds_b + (wc * 64 + j * 16 + fr) * 128 + colb);
      #pragma unroll
      for (int i = 0; i < 4; i++)
        #pragma unroll
        for (int j = 0; j < 4; j++)
          acc[i][j] = __builtin_amdgcn_mfma_f32_16x16x32_bf16(af[i], bf[j], acc[i][j], 0, 0, 0);
    }
    __syncthreads();
  }
  #pragma unroll
  for (int i = 0; i < 4; i++) {
    #pragma unroll
    for (int j = 0; j < 4; j++) {
      int col = n0 + wc * 64 + j * 16 + fr;
      #pragma unroll
      for (int r = 0; r < 4; r++) {
        int row = m0 + wr * 64 + i * 16 + fq * 4 + r;
        float c = acc[i][j][r] + bias[col];
        if (EPI == EPI_QKV) {
          int which = (col >= 1536) ? 2 : ((col >= 768) ? 1 : 0);
          int c2 = col - which * 768;
          if (which == 0) c *= 0.125f;
          unsigned short* dst = reinterpret_cast<unsigned short*>(outp) + (size_t)which * 8192 * 768;
          int bb = row >> 12, sl = row & 4095, hh = c2 >> 6, dh = c2 & 63;
          dst[(((size_t)(bb * 12 + hh)) * 4096 + sl) * 64 + dh] = f2bf(c);
        } else if (EPI == EPI_RELU) {
          c = fmaxf(c * scale, 0.0f);
          reinterpret_cast<unsigned short*>(outp)[(size_t)row * N + col] = f2bf(c);
        } else {
          c = c * scale + resid[(size_t)row * N + col];
          reinterpret_cast<float*>(outp)[(size_t)row * N + col] = c;
        }
      }
    }
  }
}

// -------- fused sliding-window attention v2 (swapped-QK flash) --------------
// grid = 768: 32 q-blocks of 128 rows x 12 h x 2 b. 4 waves, wave = 32 q-rows.
// Swapped QK^T (mfma(K,Q)) -> P^T in regs, key-reduce = in-lane + 2 shfl.
// K: swizzled LDS dbuf; V: row-major LDS dbuf w/ bit3-4 XOR source swizzle;
// P: per-wave LDS (also Q staging area). 2-phase prefetch.
__global__ __launch_bounds__(256) void attn_fused_kernel(
    const unsigned short* __restrict__ qg, const unsigned short* __restrict__ kg,
    const unsigned short* __restrict__ vg, const unsigned char* __restrict__ kpm,
    unsigned short* __restrict__ attn_out)
{
  __shared__ unsigned short lds_k[2][64 * 64];   // 16 KB
  __shared__ unsigned short lds_v[2][64 * 64];   // 16 KB
  __shared__ unsigned short lds_p[4][32 * 64];   // 16 KB (Q staging, then P)
  int bid0 = blockIdx.x;
  int bid = (bid0 & 7) * 96 + (bid0 >> 3);       // XCD swizzle (768 = 8*96)
  int qblk = bid & 31, h = (bid >> 5) % 12, b = bid / 384;
  int bh = b * 12 + h;
  int q0 = qblk * 128;
  int tid = threadIdx.x, w = tid >> 6, l = tid & 63;
  int fr = l & 15, fq = l >> 4;
  int qw0 = q0 + w * 32;
  int swzb = (((l & 7) ^ (l >> 3)) << 4);
  const char* qbase = (const char*)(qg + (size_t)bh * 4096 * 64);
  const char* kbase = (const char*)(kg + (size_t)bh * 4096 * 64);
  const char* vbase = (const char*)(vg + (size_t)bh * 4096 * 64);
  const unsigned char* kpmb = kpm + (size_t)b * 4096;

  // stage this wave's 32 Q rows into lds_p[w]
  #pragma unroll
  for (int s = 0; s < 4; s++) {
    int row = w * 32 + s * 8 + (l >> 3);
    gload16(qbase + (size_t)(q0 + row) * 128 + swzb, (char*)lds_p[w] + s * 1024);
  }

  auto stageKV = [&](int c, int buf) {
    int g0 = q0 - 256 + c * 64;
    if (g0 < 0 || g0 >= 4096) return;
    #pragma unroll
    for (int s = 0; s < 2; s++) {
      int row = w * 16 + s * 8 + (l >> 3);
      gload16(kbase + (size_t)(g0 + row) * 128 + swzb,
              (char*)lds_k[buf] + (w * 2 + s) * 1024);
    }
    #pragma unroll
    for (int s = 0; s < 2; s++) {
      int srow = w * 2 + s;                        // key-group of 8
      gload16(vbase + (size_t)(g0 + srow * 8 + (l >> 3)) * 128 + (((l & 7) * 16) ^ ((srow & 3) << 4)),
              (char*)lds_v[buf] + srow * 1024);
    }
  };

  stageKV(0, 0);
  asm volatile("s_waitcnt vmcnt(0)");
  __syncthreads();

  // Q B-frags (col=q, k=d) from lds_p[w], then lds_p becomes the P buffer
  short8 qf[2][2];
  #pragma unroll
  for (int i = 0; i < 2; i++)
    #pragma unroll
    for (int ks = 0; ks < 2; ks++)
      qf[i][ks] = *(const short8*)((const char*)lds_p[w] + (i * 16 + fr) * 128 +
                    ((ks * 64 + fq * 16) ^ ((fr & 7) << 4)));

  f32x4 acc_o[2][4] = {};
  float m_st[2] = {-3.0e38f, -3.0e38f};
  float l_st[2] = {0.0f, 0.0f};

  for (int c = 0; c < 10; c++) {
    int g0 = q0 - 256 + c * 64;
    bool valid = (g0 >= 0) && (g0 < 4096);
    if (c < 9) stageKV(c + 1, (c + 1) & 1);
    if (valid) {
      int buf = c & 1;
      unsigned int km[4];
      #pragma unroll
      for (int j = 0; j < 4; j++)
        km[j] = *(const unsigned int*)(kpmb + g0 + 16 * j + 4 * fq);
      bool anyk = __any((km[0] | km[1] | km[2] | km[3]) != 0);
      int rel = g0 - qw0;
      bool edge = anyk || (rel < -225) || (rel > 193);
      // K A-frags (row=key, k=d)
      short8 kf[4][2];
      #pragma unroll
      for (int j = 0; j < 4; j++)
        #pragma unroll
        for (int ks = 0; ks < 2; ks++)
          kf[j][ks] = *(const short8*)((const char*)lds_k[buf] + (j * 16 + fr) * 128 +
                        ((ks * 64 + fq * 16) ^ ((fr & 7) << 4)));
      // swapped QK^T: C[key][q]
      f32x4 accs[4][2] = {};
      #pragma unroll
      for (int j = 0; j < 4; j++)
        #pragma unroll
        for (int i = 0; i < 2; i++)
          #pragma unroll
          for (int ks = 0; ks < 2; ks++)
            accs[j][i] = __builtin_amdgcn_mfma_f32_16x16x32_bf16(kf[j][ks], qf[i][ks], accs[j][i], 0, 0, 0);
      // online softmax per q-tile i (lane fr = query, 16 key-values in-lane)
      #pragma unroll
      for (int i = 0; i < 2; i++) {
        float sv[4][4];
        #pragma unroll
        for (int j = 0; j < 4; j++)
          #pragma unroll
          for (int r = 0; r < 4; r++)
            sv[j][r] = accs[j][i][r];
        if (edge) {
          int base = rel + 4 * fq - fr - 16 * i;
          #pragma unroll
          for (int j = 0; j < 4; j++)
            #pragma unroll
            for (int r = 0; r < 4; r++) {
              int d = base + 16 * j + r;
              bool ok = (d >= -256) && (d <= 256) && (((km[j] >> (8 * r)) & 255u) == 0u);
              if (!ok) sv[j][r] = -1.0e9f;
            }
        }
        float mv = sv[0][0];
        #pragma unroll
        for (int j = 0; j < 4; j++)
          #pragma unroll
          for (int r = 0; r < 4; r++) mv = fmaxf(mv, sv[j][r]);
        mv = fmaxf(mv, __shfl_xor(mv, 16));
        mv = fmaxf(mv, __shfl_xor(mv, 32));
        float mo = m_st[i];
        float mn = fmaxf(mo, mv);
        float scl = __expf(mo - mn);
        float rs = 0.0f;
        unsigned int pk[4][2];
        #pragma unroll
        for (int j = 0; j < 4; j++) {
          float p0 = __expf(sv[j][0] - mn), p1 = __expf(sv[j][1] - mn);
          float p2 = __expf(sv[j][2] - mn), p3 = __expf(sv[j][3] - mn);
          rs += (p0 + p1) + (p2 + p3);
          pk[j][0] = (unsigned)f2bf(p0) | ((unsigned)f2bf(p1) << 16);
          pk[j][1] = (unsigned)f2bf(p2) | ((unsigned)f2bf(p3) << 16);
        }
        rs += __shfl_xor(rs, 16);
        rs += __shfl_xor(rs, 32);
        l_st[i] = l_st[i] * scl + rs;
        m_st[i] = mn;
        // write P row (q = i*16+fr), keys 16j+4fq..+3 packed as 8B
        char* prow = (char*)lds_p[w] + (i * 16 + fr) * 128;
        #pragma unroll
        for (int j = 0; j < 4; j++) {
          uint2 u; u.x = pk[j][0]; u.y = pk[j][1];
          *(uint2*)(prow + ((32 * j + 8 * fq) ^ ((fr & 7) << 4))) = u;
        }
        // rescale O accumulator (O-frag rows are q=4fq+r; scl lives at lane fr=q)
        #pragma unroll
        for (int r = 0; r < 4; r++) {
          float so = __shfl(scl, (l & 48) | ((l >> 2) & 12) | r);
          #pragma unroll
          for (int jd = 0; jd < 4; jd++) acc_o[i][jd][r] *= so;
        }
      }
      // P A-frags (row=q, k=key)
      short8 pf[2][2];
      #pragma unroll
      for (int i = 0; i < 2; i++)
        #pragma unroll
        for (int ks = 0; ks < 2; ks++)
          pf[i][ks] = *(const short8*)((const char*)lds_p[w] + (i * 16 + fr) * 128 +
                        ((ks * 64 + fq * 16) ^ ((fr & 7) << 4)));
      // V B-frags (k=key, col=d) from row-major lds_v, broadcast-pattern u16 reads
      #pragma unroll
      for (int jd = 0; jd < 4; jd++) {
        #pragma unroll
        for (int ks = 0; ks < 2; ks++) {
          const char* vb0 = (const char*)lds_v[buf] + (size_t)(ks * 32 + fq * 8) * 128 +
                            ((jd * 32 + 2 * fr) ^ (fq << 4));
          short8 vv;
          #pragma unroll
          for (int j = 0; j < 8; j++)
            vv[j] = *(const short*)(vb0 + j * 128);
          #pragma unroll
          for (int i = 0; i < 2; i++)
            acc_o[i][jd] = __builtin_amdgcn_mfma_f32_16x16x32_bf16(pf[i][ks], vv, acc_o[i][jd], 0, 0, 0);
        }
      }
    }
    asm volatile("s_waitcnt vmcnt(0)");
    __syncthreads();
  }
  // epilogue: divide by l (broadcast to O-frag rows) and store
  #pragma unroll
  for (int i = 0; i < 2; i++) {
    #pragma unroll
    for (int r = 0; r < 4; r++) {
      float lv = __shfl(l_st[i], (l & 48) | ((l >> 2) & 12) | r);
      float inv = 1.0f / lv;
      int qrow = qw0 + i * 16 + fq * 4 + r;
      size_t orow = ((size_t)b * 4096 + qrow) * 768 + h * 64;
      #pragma unroll
      for (int jd = 0; jd < 4; jd++)
        attn_out[orow + jd * 16 + fr] = f2bf(acc_o[i][jd][r] * inv);
    }
  }
}

extern "C" void kernel_launch(void* const* d_in, const int* in_sizes, int n_in,
                              void* d_out, int out_size, void* d_ws, size_t ws_size,
                              hipStream_t stream) {
  const float* x            = (const float*)d_in[0];
  const unsigned char* mask = (const unsigned char*)d_in[1];
  const float* Wq  = (const float*)d_in[3];
  const float* bq  = (const float*)d_in[4];
  const float* Wk  = (const float*)d_in[5];
  const float* bk  = (const float*)d_in[6];
  const float* Wv  = (const float*)d_in[7];
  const float* bv  = (const float*)d_in[8];
  const float* Wo  = (const float*)d_in[9];
  const float* bo  = (const float*)d_in[10];
  const float* ln1g = (const float*)d_in[11];
  const float* ln1b = (const float*)d_in[12];
  const float* W1  = (const float*)d_in[13];
  const float* b1  = (const float*)d_in[14];
  const float* W2  = (const float*)d_in[15];
  const float* b2  = (const float*)d_in[16];
  const float* ln2g = (const float*)d_in[17];
  const float* ln2b = (const float*)d_in[18];
  float* out = (float*)d_out;

  char* ws = (char*)d_ws;
  size_t off = 0;
  auto alloc = [&](size_t bytes) -> void* {
    void* p = ws + off;
    off += (bytes + 255) & ~(size_t)255;
    return p;
  };
  unsigned short* WTqkv = (unsigned short*)alloc((size_t)2304 * 768 * 2);
  unsigned short* WTo   = (unsigned short*)alloc((size_t)768 * 768 * 2);
  unsigned short* W1T   = (unsigned short*)alloc((size_t)3072 * 768 * 2);
  unsigned short* W2T   = (unsigned short*)alloc((size_t)768 * 3072 * 2);
  float*          bqkv  = (float*)alloc(2304 * 4);
  unsigned short* hbuf  = (unsigned short*)alloc((size_t)8192 * 768 * 2);
  unsigned short* qkv   = (unsigned short*)alloc((size_t)3 * 8192 * 768 * 2);
  unsigned short* attn  = (unsigned short*)alloc((size_t)8192 * 768 * 2);
  float* x1             = (float*)alloc((size_t)8192 * 768 * 4);
  unsigned short* h2    = (unsigned short*)alloc((size_t)8192 * 768 * 2);
  unsigned short* a1    = (unsigned short*)alloc((size_t)8192 * 3072 * 2);

  transpose_kernel<<<dim3(24, 24), 256, 0, stream>>>(Wq, WTqkv, 768, 768);
  transpose_kernel<<<dim3(24, 24), 256, 0, stream>>>(Wk, WTqkv + (size_t)768 * 768, 768, 768);
  transpose_kernel<<<dim3(24, 24), 256, 0, stream>>>(Wv, WTqkv + (size_t)1536 * 768, 768, 768);
  transpose_kernel<<<dim3(24, 24), 256, 0, stream>>>(Wo, WTo, 768, 768);
  transpose_kernel<<<dim3(24, 96), 256, 0, stream>>>(W1, W1T, 768, 3072);
  transpose_kernel<<<dim3(96, 24), 256, 0, stream>>>(W2, W2T, 3072, 768);
  catbias_kernel<<<9, 256, 0, stream>>>(bq, bk, bv, bqkv);

  ln_kernel<<<8192, 256, 0, stream>>>(x, ln1g, ln1b, hbuf);

  gemm_kernel<EPI_QKV><<<dim3(64, 18), 256, 0, stream>>>(hbuf, WTqkv, bqkv, nullptr, qkv, 8192, 2304, 768, 1.0f);

  attn_fused_kernel<<<768, 256, 0, stream>>>(qkv, qkv + (size_t)8192 * 768,
                                             qkv + (size_t)2 * 8192 * 768, mask, attn);

  gemm_kernel<EPI_RESID><<<dim3(64, 6), 256, 0, stream>>>(attn, WTo, bo, x, x1, 8192, 768, 768, 1.0f);
  ln_kernel<<<8192, 256, 0, stream>>>(x1, ln2g, ln2b, h2);
  gemm_kernel<EPI_RELU><<<dim3(64, 24), 256, 0, stream>>>(h2, W1T, b1, nullptr, a1, 8192, 3072, 768, 1.0f);
  gemm_kernel<EPI_RESID><<<dim3(64, 6), 256, 0, stream>>>(a1, W2T, b2, x1, out, 8192, 768, 3072, 1.0f);
}

// Round 4
// 286.114 us; speedup vs baseline: 1.7811x; 1.0069x over previous
//
#include <hip/hip_runtime.h>
#include <hip/hip_bf16.h>
#include <cstddef>

typedef __attribute__((ext_vector_type(8))) short short8;
typedef __attribute__((ext_vector_type(4))) float f32x4;

typedef __attribute__((address_space(1))) void as1_void;
typedef __attribute__((address_space(3))) void as3_void;

__device__ __forceinline__ void gload16(const void* g, void* lds) {
  __builtin_amdgcn_global_load_lds((as1_void*)(void*)g, (as3_void*)lds, 16, 0, 0);
}

__device__ inline unsigned short f2bf(float f) {
  union { float f; unsigned int u; } v; v.f = f;
  return (unsigned short)((v.u + 0x7FFFu + ((v.u >> 16) & 1u)) >> 16);
}

// ---------------- LayerNorm: fp32 in -> bf16 out (row = 768) ----------------
__global__ __launch_bounds__(256) void ln_kernel(const float* __restrict__ x,
    const float* __restrict__ g, const float* __restrict__ b,
    unsigned short* __restrict__ out)
{
  int row = blockIdx.x, t = threadIdx.x;
  const float* xr = x + (size_t)row * 768;
  float v0 = xr[t], v1 = xr[t + 256], v2 = xr[t + 512];
  float s = v0 + v1 + v2;
  #pragma unroll
  for (int o = 32; o > 0; o >>= 1) s += __shfl_xor(s, o);
  __shared__ float r1[4], r2[4];
  if ((t & 63) == 0) r1[t >> 6] = s;
  __syncthreads();
  float mean = (r1[0] + r1[1] + r1[2] + r1[3]) * (1.0f / 768.0f);
  float d0 = v0 - mean, d1 = v1 - mean, d2 = v2 - mean;
  float q = d0 * d0 + d1 * d1 + d2 * d2;
  #pragma unroll
  for (int o = 32; o > 0; o >>= 1) q += __shfl_xor(q, o);
  if ((t & 63) == 0) r2[t >> 6] = q;
  __syncthreads();
  float var = (r2[0] + r2[1] + r2[2] + r2[3]) * (1.0f / 768.0f);
  float rs = rsqrtf(var + 1e-6f);
  unsigned short* orow = out + (size_t)row * 768;
  orow[t]       = f2bf(g[t]       * d0 * rs + b[t]);
  orow[t + 256] = f2bf(g[t + 256] * d1 * rs + b[t + 256]);
  orow[t + 512] = f2bf(g[t + 512] * d2 * rs + b[t + 512]);
}

// ------------- transpose + fp32->bf16: W[K][N] -> WT[N][K] ------------------
__global__ __launch_bounds__(256) void transpose_kernel(const float* __restrict__ W,
    unsigned short* __restrict__ WT, int K, int N)
{
  __shared__ float tile[32][33];
  int tx = threadIdx.x & 31, ty = threadIdx.x >> 5;
  int k0 = blockIdx.x * 32, n0 = blockIdx.y * 32;
  #pragma unroll
  for (int i = 0; i < 32; i += 8)
    tile[ty + i][tx] = W[(size_t)(k0 + ty + i) * N + n0 + tx];
  __syncthreads();
  #pragma unroll
  for (int i = 0; i < 32; i += 8)
    WT[(size_t)(n0 + ty + i) * K + k0 + tx] = f2bf(tile[tx][ty + i]);
}

// -------------------- concat bias [bq|bk|bv] -> 2304 ------------------------
__global__ __launch_bounds__(256) void catbias_kernel(const float* __restrict__ bq,
    const float* __restrict__ bk, const float* __restrict__ bv, float* __restrict__ o)
{
  int i = blockIdx.x * 256 + threadIdx.x;
  o[i] = (i < 768) ? bq[i] : ((i < 1536) ? bk[i - 768] : bv[i - 1536]);
}

enum { EPI_QKV = 0, EPI_RELU = 1, EPI_RESID = 2 };

// ============ 256x256-tile 8-phase bf16 GEMM (8 waves, BK=64) ===============
// Half-tiles are K-split (A_k0,B_k0,A_k1,B_k1 = 16KB each), one staged/phase
// into the non-compute buffer. Counted vmcnt(4) + raw barrier twice per K-tile.
// Frag reads: row-pair XOR swizzle -> 2-way (free); inverse swizzle applied on
// per-lane global source so global_load_lds dest stays linear.
#define MFMA16(MQ, AF, BF)                                                     \
  __builtin_amdgcn_s_setprio(1);                                               \
  _Pragma("unroll")                                                            \
  for (int i_ = 0; i_ < 4; i_++) {                                             \
    _Pragma("unroll")                                                          \
    for (int j_ = 0; j_ < 4; j_++)                                             \
      acc[(MQ) * 4 + i_][j_] = __builtin_amdgcn_mfma_f32_16x16x32_bf16(        \
          AF[i_], BF[j_], acc[(MQ) * 4 + i_][j_], 0, 0, 0);                    \
  }                                                                            \
  __builtin_amdgcn_s_setprio(0);

#define READ_A(BUF, KH, MQ, AF)                                                \
  { const char* ab_ = &lds[BUF][(KH) * 2][0] + wr * 8192 + (MQ) * 4096 + swz;  \
    _Pragma("unroll")                                                          \
    for (int i_ = 0; i_ < 4; i_++) AF[i_] = *(const short8*)(ab_ + i_ * 1024); }

#define READ_B(BUF, KH, BF)                                                    \
  { const char* bb_ = &lds[BUF][(KH) * 2 + 1][0] + wc * 4096 + swz;            \
    _Pragma("unroll")                                                          \
    for (int j_ = 0; j_ < 4; j_++) BF[j_] = *(const short8*)(bb_ + j_ * 1024); }

template<int EPI>
__global__ __launch_bounds__(512, 1) void gemm256_kernel(
    const unsigned short* __restrict__ A, const unsigned short* __restrict__ BT,
    const float* __restrict__ bias, void* __restrict__ outp,
    int M, int N, int K, int ntn)
{
  __shared__ char lds[2][4][16384];
  int tid = threadIdx.x;
  int nwg = gridDim.x;
  int bid = ((int)blockIdx.x & 7) * (nwg >> 3) + ((int)blockIdx.x >> 3); // nwg%8==0
  int mt = bid / ntn, nt = bid % ntn;
  int m0 = mt * 256, n0 = nt * 256;
  int w = tid >> 6, l = tid & 63;
  int wr = w >> 2, wc = w & 3;
  int fr = l & 15, fq = l >> 4;
  // frag-read swizzled lane offset
  int swz = (fr >> 1) * 128 + (((((fr & 1) << 2) | fq) ^ ((fr >> 1) & 7)) << 4);
  // staging source precompute (inverse swizzle on global address)
  int t8 = tid >> 3;
  int uu = (tid & 7) ^ (t8 & 7);
  int rb = 2 * t8 + (uu >> 2);
  int kb = (uu & 3) * 8;
  const unsigned short* Asrc = A + (size_t)(m0 + rb) * K + kb;
  const unsigned short* Bsrc = BT + (size_t)(n0 + rb) * K + kb;

  auto stageP = [&](int buf, int p, int kt) {
    const unsigned short* s0 = ((p & 1) ? Bsrc : Asrc) + kt * 64 + (p >> 1) * 32;
    char* d = &lds[buf][p][0] + (w << 10);
    gload16(s0, d);
    gload16(s0 + (size_t)128 * K, d + 8192);
  };

  f32x4 acc[8][4] = {};
  // prologue: stage tile 0 fully; force its k0 halves
  stageP(0, 0, 0); stageP(0, 1, 0); stageP(0, 2, 0); stageP(0, 3, 0);
  asm volatile("s_waitcnt vmcnt(4)" ::: "memory");
  __builtin_amdgcn_s_barrier();

  int NT = K >> 6;
  for (int t = 0; t < NT - 1; ++t) {
    int R = t & 1, W = R ^ 1;
    short8 af[4], bf[4];
    // phase 0: k-step 0, M-half 0
    READ_B(R, 0, bf); READ_A(R, 0, 0, af);
    stageP(W, 0, t + 1);
    MFMA16(0, af, bf);
    // phase 1: k-step 0, M-half 1
    READ_A(R, 0, 1, af);
    stageP(W, 1, t + 1);
    MFMA16(1, af, bf);
    asm volatile("s_waitcnt vmcnt(4)" ::: "memory");   // force s(t,2),s(t,3)
    __builtin_amdgcn_s_barrier();
    // phase 2: k-step 1, M-half 0
    READ_B(R, 1, bf); READ_A(R, 1, 0, af);
    stageP(W, 2, t + 1);
    MFMA16(0, af, bf);
    // phase 3: k-step 1, M-half 1
    READ_A(R, 1, 1, af);
    stageP(W, 3, t + 1);
    MFMA16(1, af, bf);
    asm volatile("s_waitcnt vmcnt(4)" ::: "memory");   // force s(t+1,0),s(t+1,1)
    __builtin_amdgcn_s_barrier();
  }
  { // last tile: no staging; drain counts
    int R = (NT - 1) & 1;
    short8 af[4], bf[4];
    READ_B(R, 0, bf); READ_A(R, 0, 0, af);
    MFMA16(0, af, bf);
    READ_A(R, 0, 1, af);
    MFMA16(1, af, bf);
    asm volatile("s_waitcnt vmcnt(0)" ::: "memory");
    __builtin_amdgcn_s_barrier();
    READ_B(R, 1, bf); READ_A(R, 1, 0, af);
    MFMA16(0, af, bf);
    READ_A(R, 1, 1, af);
    MFMA16(1, af, bf);
  }
  // epilogue
  #pragma unroll
  for (int mi = 0; mi < 8; mi++) {
    #pragma unroll
    for (int nj = 0; nj < 4; nj++) {
      int col = n0 + wc * 64 + nj * 16 + fr;
      #pragma unroll
      for (int r = 0; r < 4; r++) {
        int row = m0 + wr * 128 + mi * 16 + fq * 4 + r;
        float c = acc[mi][nj][r] + bias[col];
        if (EPI == EPI_QKV) {
          int which = (col >= 1536) ? 2 : ((col >= 768) ? 1 : 0);
          int c2 = col - which * 768;
          if (which == 0) c *= 0.125f;
          unsigned short* dst = reinterpret_cast<unsigned short*>(outp) + (size_t)which * 8192 * 768;
          int bb = row >> 12, sl = row & 4095, hh = c2 >> 6, dh = c2 & 63;
          dst[(((size_t)(bb * 12 + hh)) * 4096 + sl) * 64 + dh] = f2bf(c);
        } else {
          c = fmaxf(c, 0.0f);
          reinterpret_cast<unsigned short*>(outp)[(size_t)row * N + col] = f2bf(c);
        }
      }
    }
  }
}

// ---------------- 128x128 bf16 MFMA GEMM (2-phase) ---------------------------
template<int EPI>
__global__ __launch_bounds__(256) void gemm_kernel(
    const unsigned short* __restrict__ A, const unsigned short* __restrict__ BT,
    const float* __restrict__ bias, const float* __restrict__ resid,
    void* __restrict__ outp, int M, int N, int K, float scale)
{
  __shared__ unsigned short lds_a[128 * 64];
  __shared__ unsigned short lds_b[128 * 64];
  int tid = threadIdx.x;
  int m0 = blockIdx.x * 128, n0 = blockIdx.y * 128;
  int w = tid >> 6, l = tid & 63;
  int wr = w >> 1, wc = w & 1;
  int fr = l & 15, fq = l >> 4;
  int lrow8 = l >> 3;
  int swzb = (((l & 7) ^ lrow8) << 4);
  const char* Ab = (const char*)A;
  const char* Bb = (const char*)BT;
  f32x4 acc[4][4] = {};
  for (int k0 = 0; k0 < K; k0 += 64) {
    #pragma unroll
    for (int s = 0; s < 4; s++) {
      int row = w * 32 + s * 8 + lrow8;
      gload16(Ab + ((size_t)(m0 + row) * K + k0) * 2 + swzb,
              (char*)lds_a + w * 4096 + s * 1024);
      gload16(Bb + ((size_t)(n0 + row) * K + k0) * 2 + swzb,
              (char*)lds_b + w * 4096 + s * 1024);
    }
    __syncthreads();
    #pragma unroll
    for (int ks = 0; ks < 2; ks++) {
      int colb = (ks * 64 + (fq << 4)) ^ ((fr & 7) << 4);
      short8 af[4], bf[4];
      #pragma unroll
      for (int i = 0; i < 4; i++)
        af[i] = *(const short8*)((const char*)lds_a + (wr * 64 + i * 16 + fr) * 128 + colb);
      #pragma unroll
      for (int j = 0; j < 4; j++)
        bf[j] = *(const short8*)((const char*)lds_b + (wc * 64 + j * 16 + fr) * 128 + colb);
      #pragma unroll
      for (int i = 0; i < 4; i++)
        #pragma unroll
        for (int j = 0; j < 4; j++)
          acc[i][j] = __builtin_amdgcn_mfma_f32_16x16x32_bf16(af[i], bf[j], acc[i][j], 0, 0, 0);
    }
    __syncthreads();
  }
  #pragma unroll
  for (int i = 0; i < 4; i++) {
    #pragma unroll
    for (int j = 0; j < 4; j++) {
      int col = n0 + wc * 64 + j * 16 + fr;
      #pragma unroll
      for (int r = 0; r < 4; r++) {
        int row = m0 + wr * 64 + i * 16 + fq * 4 + r;
        float c = acc[i][j][r] + bias[col];
        if (EPI == EPI_RELU) {
          c = fmaxf(c * scale, 0.0f);
          reinterpret_cast<unsigned short*>(outp)[(size_t)row * N + col] = f2bf(c);
        } else {
          c = c * scale + resid[(size_t)row * N + col];
          reinterpret_cast<float*>(outp)[(size_t)row * N + col] = c;
        }
      }
    }
  }
}

// -------- fused sliding-window attention v2 (swapped-QK flash) --------------
__global__ __launch_bounds__(256) void attn_fused_kernel(
    const unsigned short* __restrict__ qg, const unsigned short* __restrict__ kg,
    const unsigned short* __restrict__ vg, const unsigned char* __restrict__ kpm,
    unsigned short* __restrict__ attn_out)
{
  __shared__ unsigned short lds_k[2][64 * 64];
  __shared__ unsigned short lds_v[2][64 * 64];
  __shared__ unsigned short lds_p[4][32 * 64];
  int bid0 = blockIdx.x;
  int bid = (bid0 & 7) * 96 + (bid0 >> 3);
  int qblk = bid & 31, h = (bid >> 5) % 12, b = bid / 384;
  int bh = b * 12 + h;
  int q0 = qblk * 128;
  int tid = threadIdx.x, w = tid >> 6, l = tid & 63;
  int fr = l & 15, fq = l >> 4;
  int qw0 = q0 + w * 32;
  int swzb = (((l & 7) ^ (l >> 3)) << 4);
  const char* qbase = (const char*)(qg + (size_t)bh * 4096 * 64);
  const char* kbase = (const char*)(kg + (size_t)bh * 4096 * 64);
  const char* vbase = (const char*)(vg + (size_t)bh * 4096 * 64);
  const unsigned char* kpmb = kpm + (size_t)b * 4096;

  #pragma unroll
  for (int s = 0; s < 4; s++) {
    int row = w * 32 + s * 8 + (l >> 3);
    gload16(qbase + (size_t)(q0 + row) * 128 + swzb, (char*)lds_p[w] + s * 1024);
  }

  auto stageKV = [&](int c, int buf) {
    int g0 = q0 - 256 + c * 64;
    if (g0 < 0 || g0 >= 4096) return;
    #pragma unroll
    for (int s = 0; s < 2; s++) {
      int row = w * 16 + s * 8 + (l >> 3);
      gload16(kbase + (size_t)(g0 + row) * 128 + swzb,
              (char*)lds_k[buf] + (w * 2 + s) * 1024);
    }
    #pragma unroll
    for (int s = 0; s < 2; s++) {
      int srow = w * 2 + s;
      gload16(vbase + (size_t)(g0 + srow * 8 + (l >> 3)) * 128 + (((l & 7) * 16) ^ ((srow & 3) << 4)),
              (char*)lds_v[buf] + srow * 1024);
    }
  };

  stageKV(0, 0);
  asm volatile("s_waitcnt vmcnt(0)");
  __syncthreads();

  short8 qf[2][2];
  #pragma unroll
  for (int i = 0; i < 2; i++)
    #pragma unroll
    for (int ks = 0; ks < 2; ks++)
      qf[i][ks] = *(const short8*)((const char*)lds_p[w] + (i * 16 + fr) * 128 +
                    ((ks * 64 + fq * 16) ^ ((fr & 7) << 4)));

  f32x4 acc_o[2][4] = {};
  float m_st[2] = {-3.0e38f, -3.0e38f};
  float l_st[2] = {0.0f, 0.0f};

  for (int c = 0; c < 10; c++) {
    int g0 = q0 - 256 + c * 64;
    bool valid = (g0 >= 0) && (g0 < 4096);
    if (c < 9) stageKV(c + 1, (c + 1) & 1);
    if (valid) {
      int buf = c & 1;
      unsigned int km[4];
      #pragma unroll
      for (int j = 0; j < 4; j++)
        km[j] = *(const unsigned int*)(kpmb + g0 + 16 * j + 4 * fq);
      bool anyk = __any((km[0] | km[1] | km[2] | km[3]) != 0);
      int rel = g0 - qw0;
      bool edge = anyk || (rel < -225) || (rel > 193);
      short8 kf[4][2];
      #pragma unroll
      for (int j = 0; j < 4; j++)
        #pragma unroll
        for (int ks = 0; ks < 2; ks++)
          kf[j][ks] = *(const short8*)((const char*)lds_k[buf] + (j * 16 + fr) * 128 +
                        ((ks * 64 + fq * 16) ^ ((fr & 7) << 4)));
      f32x4 accs[4][2] = {};
      #pragma unroll
      for (int j = 0; j < 4; j++)
        #pragma unroll
        for (int i = 0; i < 2; i++)
          #pragma unroll
          for (int ks = 0; ks < 2; ks++)
            accs[j][i] = __builtin_amdgcn_mfma_f32_16x16x32_bf16(kf[j][ks], qf[i][ks], accs[j][i], 0, 0, 0);
      #pragma unroll
      for (int i = 0; i < 2; i++) {
        float sv[4][4];
        #pragma unroll
        for (int j = 0; j < 4; j++)
          #pragma unroll
          for (int r = 0; r < 4; r++)
            sv[j][r] = accs[j][i][r];
        if (edge) {
          int base = rel + 4 * fq - fr - 16 * i;
          #pragma unroll
          for (int j = 0; j < 4; j++)
            #pragma unroll
            for (int r = 0; r < 4; r++) {
              int d = base + 16 * j + r;
              bool ok = (d >= -256) && (d <= 256) && (((km[j] >> (8 * r)) & 255u) == 0u);
              if (!ok) sv[j][r] = -1.0e9f;
            }
        }
        float mv = sv[0][0];
        #pragma unroll
        for (int j = 0; j < 4; j++)
          #pragma unroll
          for (int r = 0; r < 4; r++) mv = fmaxf(mv, sv[j][r]);
        mv = fmaxf(mv, __shfl_xor(mv, 16));
        mv = fmaxf(mv, __shfl_xor(mv, 32));
        float mo = m_st[i];
        float mn = fmaxf(mo, mv);
        float scl = __expf(mo - mn);
        float rs = 0.0f;
        unsigned int pk[4][2];
        #pragma unroll
        for (int j = 0; j < 4; j++) {
          float p0 = __expf(sv[j][0] - mn), p1 = __expf(sv[j][1] - mn);
          float p2 = __expf(sv[j][2] - mn), p3 = __expf(sv[j][3] - mn);
          rs += (p0 + p1) + (p2 + p3);
          pk[j][0] = (unsigned)f2bf(p0) | ((unsigned)f2bf(p1) << 16);
          pk[j][1] = (unsigned)f2bf(p2) | ((unsigned)f2bf(p3) << 16);
        }
        rs += __shfl_xor(rs, 16);
        rs += __shfl_xor(rs, 32);
        l_st[i] = l_st[i] * scl + rs;
        m_st[i] = mn;
        char* prow = (char*)lds_p[w] + (i * 16 + fr) * 128;
        #pragma unroll
        for (int j = 0; j < 4; j++) {
          uint2 u; u.x = pk[j][0]; u.y = pk[j][1];
          *(uint2*)(prow + ((32 * j + 8 * fq) ^ ((fr & 7) << 4))) = u;
        }
        #pragma unroll
        for (int r = 0; r < 4; r++) {
          float so = __shfl(scl, (l & 48) | ((l >> 2) & 12) | r);
          #pragma unroll
          for (int jd = 0; jd < 4; jd++) acc_o[i][jd][r] *= so;
        }
      }
      short8 pf[2][2];
      #pragma unroll
      for (int i = 0; i < 2; i++)
        #pragma unroll
        for (int ks = 0; ks < 2; ks++)
          pf[i][ks] = *(const short8*)((const char*)lds_p[w] + (i * 16 + fr) * 128 +
                        ((ks * 64 + fq * 16) ^ ((fr & 7) << 4)));
      #pragma unroll
      for (int jd = 0; jd < 4; jd++) {
        #pragma unroll
        for (int ks = 0; ks < 2; ks++) {
          const char* vb0 = (const char*)lds_v[buf] + (size_t)(ks * 32 + fq * 8) * 128 +
                            ((jd * 32 + 2 * fr) ^ (fq << 4));
          short8 vv;
          #pragma unroll
          for (int j = 0; j < 8; j++)
            vv[j] = *(const short*)(vb0 + j * 128);
          #pragma unroll
          for (int i = 0; i < 2; i++)
            acc_o[i][jd] = __builtin_amdgcn_mfma_f32_16x16x32_bf16(pf[i][ks], vv, acc_o[i][jd], 0, 0, 0);
        }
      }
    }
    asm volatile("s_waitcnt vmcnt(0)");
    __syncthreads();
  }
  #pragma unroll
  for (int i = 0; i < 2; i++) {
    #pragma unroll
    for (int r = 0; r < 4; r++) {
      float lv = __shfl(l_st[i], (l & 48) | ((l >> 2) & 12) | r);
      float inv = 1.0f / lv;
      int qrow = qw0 + i * 16 + fq * 4 + r;
      size_t orow = ((size_t)b * 4096 + qrow) * 768 + h * 64;
      #pragma unroll
      for (int jd = 0; jd < 4; jd++)
        attn_out[orow + jd * 16 + fr] = f2bf(acc_o[i][jd][r] * inv);
    }
  }
}

extern "C" void kernel_launch(void* const* d_in, const int* in_sizes, int n_in,
                              void* d_out, int out_size, void* d_ws, size_t ws_size,
                              hipStream_t stream) {
  const float* x            = (const float*)d_in[0];
  const unsigned char* mask = (const unsigned char*)d_in[1];
  const float* Wq  = (const float*)d_in[3];
  const float* bq  = (const float*)d_in[4];
  const float* Wk  = (const float*)d_in[5];
  const float* bk  = (const float*)d_in[6];
  const float* Wv  = (const float*)d_in[7];
  const float* bv  = (const float*)d_in[8];
  const float* Wo  = (const float*)d_in[9];
  const float* bo  = (const float*)d_in[10];
  const float* ln1g = (const float*)d_in[11];
  const float* ln1b = (const float*)d_in[12];
  const float* W1  = (const float*)d_in[13];
  const float* b1  = (const float*)d_in[14];
  const float* W2  = (const float*)d_in[15];
  const float* b2  = (const float*)d_in[16];
  const float* ln2g = (const float*)d_in[17];
  const float* ln2b = (const float*)d_in[18];
  float* out = (float*)d_out;

  char* ws = (char*)d_ws;
  size_t off = 0;
  auto alloc = [&](size_t bytes) -> void* {
    void* p = ws + off;
    off += (bytes + 255) & ~(size_t)255;
    return p;
  };
  unsigned short* WTqkv = (unsigned short*)alloc((size_t)2304 * 768 * 2);
  unsigned short* WTo   = (unsigned short*)alloc((size_t)768 * 768 * 2);
  unsigned short* W1T   = (unsigned short*)alloc((size_t)3072 * 768 * 2);
  unsigned short* W2T   = (unsigned short*)alloc((size_t)768 * 3072 * 2);
  float*          bqkv  = (float*)alloc(2304 * 4);
  unsigned short* hbuf  = (unsigned short*)alloc((size_t)8192 * 768 * 2);
  unsigned short* qkv   = (unsigned short*)alloc((size_t)3 * 8192 * 768 * 2);
  unsigned short* attn  = (unsigned short*)alloc((size_t)8192 * 768 * 2);
  float* x1             = (float*)alloc((size_t)8192 * 768 * 4);
  unsigned short* h2    = (unsigned short*)alloc((size_t)8192 * 768 * 2);
  unsigned short* a1    = (unsigned short*)alloc((size_t)8192 * 3072 * 2);

  transpose_kernel<<<dim3(24, 24), 256, 0, stream>>>(Wq, WTqkv, 768, 768);
  transpose_kernel<<<dim3(24, 24), 256, 0, stream>>>(Wk, WTqkv + (size_t)768 * 768, 768, 768);
  transpose_kernel<<<dim3(24, 24), 256, 0, stream>>>(Wv, WTqkv + (size_t)1536 * 768, 768, 768);
  transpose_kernel<<<dim3(24, 24), 256, 0, stream>>>(Wo, WTo, 768, 768);
  transpose_kernel<<<dim3(24, 96), 256, 0, stream>>>(W1, W1T, 768, 3072);
  transpose_kernel<<<dim3(96, 24), 256, 0, stream>>>(W2, W2T, 3072, 768);
  catbias_kernel<<<9, 256, 0, stream>>>(bq, bk, bv, bqkv);

  ln_kernel<<<8192, 256, 0, stream>>>(x, ln1g, ln1b, hbuf);

  gemm256_kernel<EPI_QKV><<<288, 512, 0, stream>>>(hbuf, WTqkv, bqkv, qkv, 8192, 2304, 768, 9);

  attn_fused_kernel<<<768, 256, 0, stream>>>(qkv, qkv + (size_t)8192 * 768,
                                             qkv + (size_t)2 * 8192 * 768, mask, attn);

  gemm_kernel<EPI_RESID><<<dim3(64, 6), 256, 0, stream>>>(attn, WTo, bo, x, x1, 8192, 768, 768, 1.0f);
  ln_kernel<<<8192, 256, 0, stream>>>(x1, ln2g, ln2b, h2);
  gemm256_kernel<EPI_RELU><<<384, 512, 0, stream>>>(h2, W1T, b1, a1, 8192, 3072, 768, 12);
  gemm_kernel<EPI_RESID><<<dim3(64, 6), 256, 0, stream>>>(a1, W2T, b2, x1, out, 8192, 768, 3072, 1.0f);
}

// Round 5
// 271.863 us; speedup vs baseline: 1.8744x; 1.0524x over previous
//
#include <hip/hip_runtime.h>
#include <hip/hip_bf16.h>
#include <cstddef>

typedef __attribute__((ext_vector_type(8))) short short8;
typedef __attribute__((ext_vector_type(4))) float f32x4;
typedef __attribute__((ext_vector_type(4))) unsigned short us4;

typedef __attribute__((address_space(1))) void as1_void;
typedef __attribute__((address_space(3))) void as3_void;

__device__ __forceinline__ void gload16(const void* g, void* lds) {
  __builtin_amdgcn_global_load_lds((as1_void*)(void*)g, (as3_void*)lds, 16, 0, 0);
}

__device__ inline unsigned short f2bf(float f) {
  union { float f; unsigned int u; } v; v.f = f;
  return (unsigned short)((v.u + 0x7FFFu + ((v.u >> 16) & 1u)) >> 16);
}

// ---------------- LayerNorm: fp32 in -> bf16 out (row = 768) ----------------
__global__ __launch_bounds__(256) void ln_kernel(const float* __restrict__ x,
    const float* __restrict__ g, const float* __restrict__ b,
    unsigned short* __restrict__ out)
{
  int row = blockIdx.x, t = threadIdx.x;
  const float* xr = x + (size_t)row * 768;
  float v0 = xr[t], v1 = xr[t + 256], v2 = xr[t + 512];
  float s = v0 + v1 + v2;
  #pragma unroll
  for (int o = 32; o > 0; o >>= 1) s += __shfl_xor(s, o);
  __shared__ float r1[4], r2[4];
  if ((t & 63) == 0) r1[t >> 6] = s;
  __syncthreads();
  float mean = (r1[0] + r1[1] + r1[2] + r1[3]) * (1.0f / 768.0f);
  float d0 = v0 - mean, d1 = v1 - mean, d2 = v2 - mean;
  float q = d0 * d0 + d1 * d1 + d2 * d2;
  #pragma unroll
  for (int o = 32; o > 0; o >>= 1) q += __shfl_xor(q, o);
  if ((t & 63) == 0) r2[t >> 6] = q;
  __syncthreads();
  float var = (r2[0] + r2[1] + r2[2] + r2[3]) * (1.0f / 768.0f);
  float rs = rsqrtf(var + 1e-6f);
  unsigned short* orow = out + (size_t)row * 768;
  orow[t]       = f2bf(g[t]       * d0 * rs + b[t]);
  orow[t + 256] = f2bf(g[t + 256] * d1 * rs + b[t + 256]);
  orow[t + 512] = f2bf(g[t + 512] * d2 * rs + b[t + 512]);
}

// ------------- transpose + fp32->bf16: W[K][N] -> WT[N][K] ------------------
__global__ __launch_bounds__(256) void transpose_kernel(const float* __restrict__ W,
    unsigned short* __restrict__ WT, int K, int N)
{
  __shared__ float tile[32][33];
  int tx = threadIdx.x & 31, ty = threadIdx.x >> 5;
  int k0 = blockIdx.x * 32, n0 = blockIdx.y * 32;
  #pragma unroll
  for (int i = 0; i < 32; i += 8)
    tile[ty + i][tx] = W[(size_t)(k0 + ty + i) * N + n0 + tx];
  __syncthreads();
  #pragma unroll
  for (int i = 0; i < 32; i += 8)
    WT[(size_t)(n0 + ty + i) * K + k0 + tx] = f2bf(tile[tx][ty + i]);
}

// -------------------- concat bias [bq|bk|bv] -> 2304 ------------------------
__global__ __launch_bounds__(256) void catbias_kernel(const float* __restrict__ bq,
    const float* __restrict__ bk, const float* __restrict__ bv, float* __restrict__ o)
{
  int i = blockIdx.x * 256 + threadIdx.x;
  o[i] = (i < 768) ? bq[i] : ((i < 1536) ? bk[i - 768] : bv[i - 1536]);
}

enum { EPI_QKV = 0, EPI_RELU = 1, EPI_RESID = 2 };

// ======= 128x256-tile pipelined bf16 GEMM: 8 waves, BK=64, 96KB LDS =========
// Per K-tile: 2 phases (k-halves). Each phase: 8 ds_read_b128 frags + 3
// counted staging issues (A-half 8KB, B-half 2x8KB) + 16 MFMA + vmcnt(3) +
// barrier. vmcnt never drains to 0 in the loop (T3/T4). Frag reads use the
// row-pair XOR swizzle (2-way = free); inverse swizzle on the per-lane global
// source keeps global_load_lds destinations linear (rule 21).
template<int EPI>
__global__ __launch_bounds__(512, 1) void gemmP_kernel(
    const unsigned short* __restrict__ A, const unsigned short* __restrict__ BT,
    const float* __restrict__ bias, const float* __restrict__ resid,
    void* __restrict__ outp, int M, int N, int K, int ntn)
{
  __shared__ char lds[2][49152];   // per buf: A [2][8192], B [2][16384]
  int tid = threadIdx.x;
  int nwg = gridDim.x;
  int bid = ((int)blockIdx.x & 7) * (nwg >> 3) + ((int)blockIdx.x >> 3);
  int mt = bid / ntn, nt = bid % ntn;
  int m0 = mt * 128, n0 = nt * 256;
  int w = tid >> 6, l = tid & 63;
  int wr = w >> 2, wc = w & 3;
  int fr = l & 15, fq = l >> 4;
  int swz = (fr >> 1) * 128 + (((((fr & 1) << 2) | fq) ^ ((fr >> 1) & 7)) << 4);
  int t8 = tid >> 3;
  int uu = (tid & 7) ^ (t8 & 7);
  int rb = 2 * t8 + (uu >> 2);
  int kb = (uu & 3) * 8;
  const unsigned short* Asrc  = A  + (size_t)(m0 + rb) * K + kb;
  const unsigned short* Bsrc0 = BT + (size_t)(n0 + rb) * K + kb;
  const unsigned short* Bsrc1 = BT + (size_t)(n0 + 128 + rb) * K + kb;

  auto stage = [&](int buf, int kt, int h) {
    int ko = kt * 64 + h * 32;
    char* dA = &lds[buf][0] + h * 8192 + (w << 10);
    char* dB = &lds[buf][16384] + h * 16384 + (w << 10);
    gload16(Asrc + ko, dA);
    gload16(Bsrc0 + ko, dB);
    gload16(Bsrc1 + ko, dB + 8192);
  };

  f32x4 acc[4][4] = {};

#define GP_COMPUTE(RBUF, H)                                                    \
  { short8 af[4], bf[4];                                                       \
    const char* ab_ = &lds[RBUF][0] + (H) * 8192 + wr * 4096 + swz;            \
    const char* bb_ = &lds[RBUF][16384] + (H) * 16384 + wc * 4096 + swz;       \
    _Pragma("unroll")                                                          \
    for (int i_ = 0; i_ < 4; i_++) af[i_] = *(const short8*)(ab_ + i_ * 1024); \
    _Pragma("unroll")                                                          \
    for (int j_ = 0; j_ < 4; j_++) bf[j_] = *(const short8*)(bb_ + j_ * 1024); \
    __builtin_amdgcn_s_setprio(1);                                             \
    _Pragma("unroll")                                                          \
    for (int i_ = 0; i_ < 4; i_++)                                             \
      _Pragma("unroll")                                                        \
      for (int j_ = 0; j_ < 4; j_++)                                           \
        acc[i_][j_] = __builtin_amdgcn_mfma_f32_16x16x32_bf16(                 \
            af[i_], bf[j_], acc[i_][j_], 0, 0, 0);                             \
    __builtin_amdgcn_s_setprio(0); }

  stage(0, 0, 0); stage(0, 0, 1);
  asm volatile("s_waitcnt vmcnt(3)" ::: "memory");
  __builtin_amdgcn_s_barrier();

  int NT = K >> 6;
  for (int t = 0; t < NT - 1; ++t) {
    int R = t & 1, W = R ^ 1;
    GP_COMPUTE(R, 0);
    stage(W, t + 1, 0);
    asm volatile("s_waitcnt vmcnt(3)" ::: "memory");
    __builtin_amdgcn_s_barrier();
    GP_COMPUTE(R, 1);
    stage(W, t + 1, 1);
    asm volatile("s_waitcnt vmcnt(3)" ::: "memory");
    __builtin_amdgcn_s_barrier();
  }
  {
    int R = (NT - 1) & 1;
    GP_COMPUTE(R, 0);
    asm volatile("s_waitcnt vmcnt(0)" ::: "memory");
    __builtin_amdgcn_s_barrier();
    GP_COMPUTE(R, 1);
  }
#undef GP_COMPUTE

  // epilogue
  #pragma unroll
  for (int nj = 0; nj < 4; nj++) {
    int col = n0 + wc * 64 + nj * 16 + fr;
    float bs = bias[col];
    if (EPI == EPI_QKV) {
      int which = (col >= 1536) ? 2 : ((col >= 768) ? 1 : 0);
      int c2 = col - which * 768;
      int hh = c2 >> 6, dh = c2 & 63;
      if (which == 2) {
        // V^T layout: [b,h,64 d,4096 s]; pack 4 consecutive s into one 8B store
        unsigned short* dstv = reinterpret_cast<unsigned short*>(outp) + (size_t)2 * 8192 * 768;
        #pragma unroll
        for (int i = 0; i < 4; i++) {
          int row0 = m0 + wr * 64 + i * 16 + fq * 4;
          int bb = row0 >> 12, sl = row0 & 4095;
          us4 pv;
          #pragma unroll
          for (int r = 0; r < 4; r++) pv[r] = f2bf(acc[i][nj][r] + bs);
          *reinterpret_cast<us4*>(&dstv[((size_t)(bb * 12 + hh) * 64 + dh) * 4096 + sl]) = pv;
        }
      } else {
        unsigned short* dst = reinterpret_cast<unsigned short*>(outp) + (size_t)which * 8192 * 768;
        #pragma unroll
        for (int i = 0; i < 4; i++) {
          #pragma unroll
          for (int r = 0; r < 4; r++) {
            int row = m0 + wr * 64 + i * 16 + fq * 4 + r;
            float c = acc[i][nj][r] + bs;
            if (which == 0) c *= 0.125f;
            int bb = row >> 12, sl = row & 4095;
            dst[(((size_t)(bb * 12 + hh)) * 4096 + sl) * 64 + dh] = f2bf(c);
          }
        }
      }
    } else if (EPI == EPI_RELU) {
      #pragma unroll
      for (int i = 0; i < 4; i++)
        #pragma unroll
        for (int r = 0; r < 4; r++) {
          int row = m0 + wr * 64 + i * 16 + fq * 4 + r;
          float c = fmaxf(acc[i][nj][r] + bs, 0.0f);
          reinterpret_cast<unsigned short*>(outp)[(size_t)row * N + col] = f2bf(c);
        }
    } else {
      #pragma unroll
      for (int i = 0; i < 4; i++)
        #pragma unroll
        for (int r = 0; r < 4; r++) {
          int row = m0 + wr * 64 + i * 16 + fq * 4 + r;
          float c = acc[i][nj][r] + bs + resid[(size_t)row * N + col];
          reinterpret_cast<float*>(outp)[(size_t)row * N + col] = c;
        }
    }
  }
}

// -------- fused sliding-window attention v3 (swapped-QK flash, V^T) ---------
// grid = 768 (3 blocks/CU exact): 32 q-blocks x 12 h x 2 b. 4 waves x 32 rows.
// K and V^T both staged via global_load_lds with source/read XOR swizzle;
// PV B-frags are ds_read_b128 from V^T rows (no scalar gathers).
__global__ __launch_bounds__(256) void attn_fused_kernel(
    const unsigned short* __restrict__ qg, const unsigned short* __restrict__ kg,
    const unsigned short* __restrict__ vtg, const unsigned char* __restrict__ kpm,
    unsigned short* __restrict__ attn_out)
{
  __shared__ unsigned short lds_k[2][64 * 64];
  __shared__ unsigned short lds_vt[2][64 * 64];
  __shared__ unsigned short lds_p[4][32 * 64];
  int bid0 = blockIdx.x;
  int bid = (bid0 & 7) * 96 + (bid0 >> 3);
  int qblk = bid & 31, h = (bid >> 5) % 12, b = bid / 384;
  int bh = b * 12 + h;
  int q0 = qblk * 128;
  int tid = threadIdx.x, w = tid >> 6, l = tid & 63;
  int fr = l & 15, fq = l >> 4;
  int qw0 = q0 + w * 32;
  int swzb = (((l & 7) ^ (l >> 3)) << 4);
  const char* qbase  = (const char*)(qg  + (size_t)bh * 4096 * 64);
  const char* kbase  = (const char*)(kg  + (size_t)bh * 4096 * 64);
  const char* vtbase = (const char*)(vtg + (size_t)bh * 64 * 4096);
  const unsigned char* kpmb = kpm + (size_t)b * 4096;

  #pragma unroll
  for (int s = 0; s < 4; s++) {
    int row = w * 32 + s * 8 + (l >> 3);
    gload16(qbase + (size_t)(q0 + row) * 128 + swzb, (char*)lds_p[w] + s * 1024);
  }

  auto stageKV = [&](int c, int buf) {
    int g0 = q0 - 256 + c * 64;
    if (g0 < 0 || g0 >= 4096) return;
    #pragma unroll
    for (int s = 0; s < 2; s++) {
      int row = w * 16 + s * 8 + (l >> 3);
      gload16(kbase + (size_t)(g0 + row) * 128 + swzb,
              (char*)lds_k[buf] + (w * 2 + s) * 1024);
      gload16(vtbase + ((size_t)row * 4096 + g0) * 2 + swzb,
              (char*)lds_vt[buf] + (w * 2 + s) * 1024);
    }
  };

  stageKV(0, 0);
  asm volatile("s_waitcnt vmcnt(0)");
  __syncthreads();

  short8 qf[2][2];
  #pragma unroll
  for (int i = 0; i < 2; i++)
    #pragma unroll
    for (int ks = 0; ks < 2; ks++)
      qf[i][ks] = *(const short8*)((const char*)lds_p[w] + (i * 16 + fr) * 128 +
                    ((ks * 64 + fq * 16) ^ ((fr & 7) << 4)));

  f32x4 acc_o[2][4] = {};
  float m_st[2] = {-3.0e38f, -3.0e38f};
  float l_st[2] = {0.0f, 0.0f};

  for (int c = 0; c < 10; c++) {
    int g0 = q0 - 256 + c * 64;
    bool valid = (g0 >= 0) && (g0 < 4096);
    if (c < 9) stageKV(c + 1, (c + 1) & 1);
    if (valid) {
      int buf = c & 1;
      unsigned int km[4];
      #pragma unroll
      for (int j = 0; j < 4; j++)
        km[j] = *(const unsigned int*)(kpmb + g0 + 16 * j + 4 * fq);
      bool anyk = __any((km[0] | km[1] | km[2] | km[3]) != 0);
      int rel = g0 - qw0;
      bool edge = anyk || (rel < -225) || (rel > 193);
      short8 kf[4][2];
      #pragma unroll
      for (int j = 0; j < 4; j++)
        #pragma unroll
        for (int ks = 0; ks < 2; ks++)
          kf[j][ks] = *(const short8*)((const char*)lds_k[buf] + (j * 16 + fr) * 128 +
                        ((ks * 64 + fq * 16) ^ ((fr & 7) << 4)));
      f32x4 accs[4][2] = {};
      #pragma unroll
      for (int j = 0; j < 4; j++)
        #pragma unroll
        for (int i = 0; i < 2; i++)
          #pragma unroll
          for (int ks = 0; ks < 2; ks++)
            accs[j][i] = __builtin_amdgcn_mfma_f32_16x16x32_bf16(kf[j][ks], qf[i][ks], accs[j][i], 0, 0, 0);
      #pragma unroll
      for (int i = 0; i < 2; i++) {
        float sv[4][4];
        #pragma unroll
        for (int j = 0; j < 4; j++)
          #pragma unroll
          for (int r = 0; r < 4; r++)
            sv[j][r] = accs[j][i][r];
        if (edge) {
          int base = rel + 4 * fq - fr - 16 * i;
          #pragma unroll
          for (int j = 0; j < 4; j++)
            #pragma unroll
            for (int r = 0; r < 4; r++) {
              int d = base + 16 * j + r;
              bool ok = (d >= -256) && (d <= 256) && (((km[j] >> (8 * r)) & 255u) == 0u);
              if (!ok) sv[j][r] = -1.0e9f;
            }
        }
        float mv = sv[0][0];
        #pragma unroll
        for (int j = 0; j < 4; j++)
          #pragma unroll
          for (int r = 0; r < 4; r++) mv = fmaxf(mv, sv[j][r]);
        mv = fmaxf(mv, __shfl_xor(mv, 16));
        mv = fmaxf(mv, __shfl_xor(mv, 32));
        float mo = m_st[i];
        float mn = fmaxf(mo, mv);
        float scl = __expf(mo - mn);
        float rs = 0.0f;
        unsigned int pk[4][2];
        #pragma unroll
        for (int j = 0; j < 4; j++) {
          float p0 = __expf(sv[j][0] - mn), p1 = __expf(sv[j][1] - mn);
          float p2 = __expf(sv[j][2] - mn), p3 = __expf(sv[j][3] - mn);
          rs += (p0 + p1) + (p2 + p3);
          pk[j][0] = (unsigned)f2bf(p0) | ((unsigned)f2bf(p1) << 16);
          pk[j][1] = (unsigned)f2bf(p2) | ((unsigned)f2bf(p3) << 16);
        }
        rs += __shfl_xor(rs, 16);
        rs += __shfl_xor(rs, 32);
        l_st[i] = l_st[i] * scl + rs;
        m_st[i] = mn;
        char* prow = (char*)lds_p[w] + (i * 16 + fr) * 128;
        #pragma unroll
        for (int j = 0; j < 4; j++) {
          uint2 u; u.x = pk[j][0]; u.y = pk[j][1];
          *(uint2*)(prow + ((32 * j + 8 * fq) ^ ((fr & 7) << 4))) = u;
        }
        #pragma unroll
        for (int r = 0; r < 4; r++) {
          float so = __shfl(scl, (l & 48) | ((l >> 2) & 12) | r);
          #pragma unroll
          for (int jd = 0; jd < 4; jd++) acc_o[i][jd][r] *= so;
        }
      }
      short8 pf[2][2];
      #pragma unroll
      for (int i = 0; i < 2; i++)
        #pragma unroll
        for (int ks = 0; ks < 2; ks++)
          pf[i][ks] = *(const short8*)((const char*)lds_p[w] + (i * 16 + fr) * 128 +
                        ((ks * 64 + fq * 16) ^ ((fr & 7) << 4)));
      short8 vf[4][2];
      #pragma unroll
      for (int jd = 0; jd < 4; jd++)
        #pragma unroll
        for (int ks = 0; ks < 2; ks++)
          vf[jd][ks] = *(const short8*)((const char*)lds_vt[buf] + (jd * 16 + fr) * 128 +
                        ((ks * 64 + fq * 16) ^ ((fr & 7) << 4)));
      #pragma unroll
      for (int i = 0; i < 2; i++)
        #pragma unroll
        for (int jd = 0; jd < 4; jd++)
          #pragma unroll
          for (int ks = 0; ks < 2; ks++)
            acc_o[i][jd] = __builtin_amdgcn_mfma_f32_16x16x32_bf16(pf[i][ks], vf[jd][ks], acc_o[i][jd], 0, 0, 0);
    }
    asm volatile("s_waitcnt vmcnt(0)");
    __syncthreads();
  }
  #pragma unroll
  for (int i = 0; i < 2; i++) {
    #pragma unroll
    for (int r = 0; r < 4; r++) {
      float lv = __shfl(l_st[i], (l & 48) | ((l >> 2) & 12) | r);
      float inv = 1.0f / lv;
      int qrow = qw0 + i * 16 + fq * 4 + r;
      size_t orow = ((size_t)b * 4096 + qrow) * 768 + h * 64;
      #pragma unroll
      for (int jd = 0; jd < 4; jd++)
        attn_out[orow + jd * 16 + fr] = f2bf(acc_o[i][jd][r] * inv);
    }
  }
}

extern "C" void kernel_launch(void* const* d_in, const int* in_sizes, int n_in,
                              void* d_out, int out_size, void* d_ws, size_t ws_size,
                              hipStream_t stream) {
  const float* x            = (const float*)d_in[0];
  const unsigned char* mask = (const unsigned char*)d_in[1];
  const float* Wq  = (const float*)d_in[3];
  const float* bq  = (const float*)d_in[4];
  const float* Wk  = (const float*)d_in[5];
  const float* bk  = (const float*)d_in[6];
  const float* Wv  = (const float*)d_in[7];
  const float* bv  = (const float*)d_in[8];
  const float* Wo  = (const float*)d_in[9];
  const float* bo  = (const float*)d_in[10];
  const float* ln1g = (const float*)d_in[11];
  const float* ln1b = (const float*)d_in[12];
  const float* W1  = (const float*)d_in[13];
  const float* b1  = (const float*)d_in[14];
  const float* W2  = (const float*)d_in[15];
  const float* b2  = (const float*)d_in[16];
  const float* ln2g = (const float*)d_in[17];
  const float* ln2b = (const float*)d_in[18];
  float* out = (float*)d_out;

  char* ws = (char*)d_ws;
  size_t off = 0;
  auto alloc = [&](size_t bytes) -> void* {
    void* p = ws + off;
    off += (bytes + 255) & ~(size_t)255;
    return p;
  };
  unsigned short* WTqkv = (unsigned short*)alloc((size_t)2304 * 768 * 2);
  unsigned short* WTo   = (unsigned short*)alloc((size_t)768 * 768 * 2);
  unsigned short* W1T   = (unsigned short*)alloc((size_t)3072 * 768 * 2);
  unsigned short* W2T   = (unsigned short*)alloc((size_t)768 * 3072 * 2);
  float*          bqkv  = (float*)alloc(2304 * 4);
  unsigned short* hbuf  = (unsigned short*)alloc((size_t)8192 * 768 * 2);
  unsigned short* qkv   = (unsigned short*)alloc((size_t)3 * 8192 * 768 * 2);
  unsigned short* attn  = (unsigned short*)alloc((size_t)8192 * 768 * 2);
  float* x1             = (float*)alloc((size_t)8192 * 768 * 4);
  unsigned short* h2    = (unsigned short*)alloc((size_t)8192 * 768 * 2);
  unsigned short* a1    = (unsigned short*)alloc((size_t)8192 * 3072 * 2);

  transpose_kernel<<<dim3(24, 24), 256, 0, stream>>>(Wq, WTqkv, 768, 768);
  transpose_kernel<<<dim3(24, 24), 256, 0, stream>>>(Wk, WTqkv + (size_t)768 * 768, 768, 768);
  transpose_kernel<<<dim3(24, 24), 256, 0, stream>>>(Wv, WTqkv + (size_t)1536 * 768, 768, 768);
  transpose_kernel<<<dim3(24, 24), 256, 0, stream>>>(Wo, WTo, 768, 768);
  transpose_kernel<<<dim3(24, 96), 256, 0, stream>>>(W1, W1T, 768, 3072);
  transpose_kernel<<<dim3(96, 24), 256, 0, stream>>>(W2, W2T, 3072, 768);
  catbias_kernel<<<9, 256, 0, stream>>>(bq, bk, bv, bqkv);

  ln_kernel<<<8192, 256, 0, stream>>>(x, ln1g, ln1b, hbuf);

  gemmP_kernel<EPI_QKV><<<576, 512, 0, stream>>>(hbuf, WTqkv, bqkv, nullptr, qkv, 8192, 2304, 768, 9);

  attn_fused_kernel<<<768, 256, 0, stream>>>(qkv, qkv + (size_t)8192 * 768,
                                             qkv + (size_t)2 * 8192 * 768, mask, attn);

  gemmP_kernel<EPI_RESID><<<192, 512, 0, stream>>>(attn, WTo, bo, x, x1, 8192, 768, 768, 3);
  ln_kernel<<<8192, 256, 0, stream>>>(x1, ln2g, ln2b, h2);
  gemmP_kernel<EPI_RELU><<<768, 512, 0, stream>>>(h2, W1T, b1, nullptr, a1, 8192, 3072, 768, 12);
  gemmP_kernel<EPI_RESID><<<192, 512, 0, stream>>>(a1, W2T, b2, x1, out, 8192, 768, 3072, 3);
}

// Round 6
// 265.783 us; speedup vs baseline: 1.9173x; 1.0229x over previous
//
#include <hip/hip_runtime.h>
#include <hip/hip_bf16.h>
#include <cstddef>

typedef __attribute__((ext_vector_type(8))) short short8;
typedef __attribute__((ext_vector_type(4))) float f32x4;
typedef __attribute__((ext_vector_type(4))) unsigned short us4;

typedef __attribute__((address_space(1))) void as1_void;
typedef __attribute__((address_space(3))) void as3_void;

__device__ __forceinline__ void gload16(const void* g, void* lds) {
  __builtin_amdgcn_global_load_lds((as1_void*)(void*)g, (as3_void*)lds, 16, 0, 0);
}

__device__ inline unsigned short f2bf(float f) {
  union { float f; unsigned int u; } v; v.f = f;
  return (unsigned short)((v.u + 0x7FFFu + ((v.u >> 16) & 1u)) >> 16);
}

// v_exp_f32 computes 2^x directly (scores are pre-scaled by log2e)
__device__ __forceinline__ float exp2v(float x) {
  float r; asm("v_exp_f32 %0, %1" : "=v"(r) : "v"(x)); return r;
}
// pack two f32 -> two bf16 (RNE) in one instruction
__device__ __forceinline__ unsigned cvtpk(float a, float b) {
  unsigned r; asm("v_cvt_pk_bf16_f32 %0, %1, %2" : "=v"(r) : "v"(a), "v"(b)); return r;
}

// ---------------- LayerNorm: fp32 in -> bf16 out (row = 768) ----------------
__global__ __launch_bounds__(256) void ln_kernel(const float* __restrict__ x,
    const float* __restrict__ g, const float* __restrict__ b,
    unsigned short* __restrict__ out)
{
  int row = blockIdx.x, t = threadIdx.x;
  const float* xr = x + (size_t)row * 768;
  float v0 = xr[t], v1 = xr[t + 256], v2 = xr[t + 512];
  float s = v0 + v1 + v2;
  #pragma unroll
  for (int o = 32; o > 0; o >>= 1) s += __shfl_xor(s, o);
  __shared__ float r1[4], r2[4];
  if ((t & 63) == 0) r1[t >> 6] = s;
  __syncthreads();
  float mean = (r1[0] + r1[1] + r1[2] + r1[3]) * (1.0f / 768.0f);
  float d0 = v0 - mean, d1 = v1 - mean, d2 = v2 - mean;
  float q = d0 * d0 + d1 * d1 + d2 * d2;
  #pragma unroll
  for (int o = 32; o > 0; o >>= 1) q += __shfl_xor(q, o);
  if ((t & 63) == 0) r2[t >> 6] = q;
  __syncthreads();
  float var = (r2[0] + r2[1] + r2[2] + r2[3]) * (1.0f / 768.0f);
  float rs = rsqrtf(var + 1e-6f);
  unsigned short* orow = out + (size_t)row * 768;
  orow[t]       = f2bf(g[t]       * d0 * rs + b[t]);
  orow[t + 256] = f2bf(g[t + 256] * d1 * rs + b[t + 256]);
  orow[t + 512] = f2bf(g[t + 512] * d2 * rs + b[t + 512]);
}

// ------------- transpose + fp32->bf16: W[K][N] -> WT[N][K] ------------------
__global__ __launch_bounds__(256) void transpose_kernel(const float* __restrict__ W,
    unsigned short* __restrict__ WT, int K, int N)
{
  __shared__ float tile[32][33];
  int tx = threadIdx.x & 31, ty = threadIdx.x >> 5;
  int k0 = blockIdx.x * 32, n0 = blockIdx.y * 32;
  #pragma unroll
  for (int i = 0; i < 32; i += 8)
    tile[ty + i][tx] = W[(size_t)(k0 + ty + i) * N + n0 + tx];
  __syncthreads();
  #pragma unroll
  for (int i = 0; i < 32; i += 8)
    WT[(size_t)(n0 + ty + i) * K + k0 + tx] = f2bf(tile[tx][ty + i]);
}

// -------------------- concat bias [bq|bk|bv] -> 2304 ------------------------
__global__ __launch_bounds__(256) void catbias_kernel(const float* __restrict__ bq,
    const float* __restrict__ bk, const float* __restrict__ bv, float* __restrict__ o)
{
  int i = blockIdx.x * 256 + threadIdx.x;
  o[i] = (i < 768) ? bq[i] : ((i < 1536) ? bk[i - 768] : bv[i - 1536]);
}

enum { EPI_QKV = 0, EPI_RELU = 1, EPI_RESID = 2 };

// ======= 128x256-tile pipelined bf16 GEMM: 8 waves, BK=64, 144KB LDS ========
// 3 LDS buffers, prefetch depth 2 (12 loads in flight/wave). Per K-tile: 2
// phases; each phase: stage 3 gloads (issue-early) + 8 ds_read_b128 + 16 MFMA
// + vmcnt(9) + barrier. vmcnt never drains to 0 in the main loop.
template<int EPI>
__global__ __launch_bounds__(512, 1) void gemmP_kernel(
    const unsigned short* __restrict__ A, const unsigned short* __restrict__ BT,
    const float* __restrict__ bias, const float* __restrict__ resid,
    void* __restrict__ outp, int M, int N, int K, int ntn)
{
  __shared__ char lds[3][49152];   // per buf: A [2][8192], B [2][16384]
  int tid = threadIdx.x;
  int nwg = gridDim.x;
  int bid = ((int)blockIdx.x & 7) * (nwg >> 3) + ((int)blockIdx.x >> 3);
  int mt = bid / ntn, nt = bid % ntn;
  int m0 = mt * 128, n0 = nt * 256;
  int w = tid >> 6, l = tid & 63;
  int wr = w >> 2, wc = w & 3;
  int fr = l & 15, fq = l >> 4;
  int swz = (fr >> 1) * 128 + (((((fr & 1) << 2) | fq) ^ ((fr >> 1) & 7)) << 4);
  int t8 = tid >> 3;
  int uu = (tid & 7) ^ (t8 & 7);
  int rb = 2 * t8 + (uu >> 2);
  int kb = (uu & 3) * 8;
  const unsigned short* Asrc  = A  + (size_t)(m0 + rb) * K + kb;
  const unsigned short* Bsrc0 = BT + (size_t)(n0 + rb) * K + kb;
  const unsigned short* Bsrc1 = BT + (size_t)(n0 + 128 + rb) * K + kb;

  auto stage = [&](int buf, int kt, int h) {
    int ko = kt * 64 + h * 32;
    char* dA = &lds[buf][0] + h * 8192 + (w << 10);
    char* dB = &lds[buf][16384] + h * 16384 + (w << 10);
    gload16(Asrc + ko, dA);
    gload16(Bsrc0 + ko, dB);
    gload16(Bsrc1 + ko, dB + 8192);
  };

  f32x4 acc[4][4] = {};

#define GP_COMPUTE(RBUF, H)                                                    \
  { short8 af[4], bf[4];                                                       \
    const char* ab_ = &lds[RBUF][0] + (H) * 8192 + wr * 4096 + swz;            \
    const char* bb_ = &lds[RBUF][16384] + (H) * 16384 + wc * 4096 + swz;       \
    _Pragma("unroll")                                                          \
    for (int i_ = 0; i_ < 4; i_++) af[i_] = *(const short8*)(ab_ + i_ * 1024); \
    _Pragma("unroll")                                                          \
    for (int j_ = 0; j_ < 4; j_++) bf[j_] = *(const short8*)(bb_ + j_ * 1024); \
    __builtin_amdgcn_s_setprio(1);                                             \
    _Pragma("unroll")                                                          \
    for (int i_ = 0; i_ < 4; i_++)                                             \
      _Pragma("unroll")                                                        \
      for (int j_ = 0; j_ < 4; j_++)                                           \
        acc[i_][j_] = __builtin_amdgcn_mfma_f32_16x16x32_bf16(                 \
            af[i_], bf[j_], acc[i_][j_], 0, 0, 0);                             \
    __builtin_amdgcn_s_setprio(0); }

  // prologue: tiles 0 and 1 fully staged (12 loads in flight)
  stage(0, 0, 0); stage(0, 0, 1); stage(1, 1, 0); stage(1, 1, 1);
  asm volatile("s_waitcnt vmcnt(9)" ::: "memory");
  __builtin_amdgcn_s_barrier();

  int NT = K >> 6;
  int R = 0;
  for (int t = 0; t < NT - 2; ++t) {
    int W = (R == 0) ? 2 : R - 1;           // (t+2)%3
    stage(W, t + 2, 0);
    GP_COMPUTE(R, 0);
    asm volatile("s_waitcnt vmcnt(9)" ::: "memory");
    __builtin_amdgcn_s_barrier();
    stage(W, t + 2, 1);
    GP_COMPUTE(R, 1);
    asm volatile("s_waitcnt vmcnt(9)" ::: "memory");
    __builtin_amdgcn_s_barrier();
    R = (R == 2) ? 0 : R + 1;
  }
  // tail: tiles NT-2, NT-1 (no staging; counted drain)
  GP_COMPUTE(R, 0);
  asm volatile("s_waitcnt vmcnt(6)" ::: "memory");
  __builtin_amdgcn_s_barrier();
  GP_COMPUTE(R, 1);
  asm volatile("s_waitcnt vmcnt(3)" ::: "memory");
  __builtin_amdgcn_s_barrier();
  R = (R == 2) ? 0 : R + 1;
  GP_COMPUTE(R, 0);
  asm volatile("s_waitcnt vmcnt(0)" ::: "memory");
  __builtin_amdgcn_s_barrier();
  GP_COMPUTE(R, 1);
#undef GP_COMPUTE

  // epilogue
  #pragma unroll
  for (int nj = 0; nj < 4; nj++) {
    int col = n0 + wc * 64 + nj * 16 + fr;
    float bs = bias[col];
    if (EPI == EPI_QKV) {
      int which = (col >= 1536) ? 2 : ((col >= 768) ? 1 : 0);
      int c2 = col - which * 768;
      int hh = c2 >> 6, dh = c2 & 63;
      if (which == 2) {
        // V^T layout: [b,h,64 d,4096 s]
        unsigned short* dstv = reinterpret_cast<unsigned short*>(outp) + (size_t)2 * 8192 * 768;
        #pragma unroll
        for (int i = 0; i < 4; i++) {
          int row0 = m0 + wr * 64 + i * 16 + fq * 4;
          int bb = row0 >> 12, sl = row0 & 4095;
          us4 pv;
          #pragma unroll
          for (int r = 0; r < 4; r++) pv[r] = f2bf(acc[i][nj][r] + bs);
          *reinterpret_cast<us4*>(&dstv[((size_t)(bb * 12 + hh) * 64 + dh) * 4096 + sl]) = pv;
        }
      } else {
        unsigned short* dst = reinterpret_cast<unsigned short*>(outp) + (size_t)which * 8192 * 768;
        #pragma unroll
        for (int i = 0; i < 4; i++) {
          #pragma unroll
          for (int r = 0; r < 4; r++) {
            int row = m0 + wr * 64 + i * 16 + fq * 4 + r;
            float c = acc[i][nj][r] + bs;
            if (which == 0) c *= 0.18033688011112042f;  // 0.125 * log2(e)
            int bb = row >> 12, sl = row & 4095;
            dst[(((size_t)(bb * 12 + hh)) * 4096 + sl) * 64 + dh] = f2bf(c);
          }
        }
      }
    } else if (EPI == EPI_RELU) {
      #pragma unroll
      for (int i = 0; i < 4; i++)
        #pragma unroll
        for (int r = 0; r < 4; r++) {
          int row = m0 + wr * 64 + i * 16 + fq * 4 + r;
          float c = fmaxf(acc[i][nj][r] + bs, 0.0f);
          reinterpret_cast<unsigned short*>(outp)[(size_t)row * N + col] = f2bf(c);
        }
    } else {
      #pragma unroll
      for (int i = 0; i < 4; i++)
        #pragma unroll
        for (int r = 0; r < 4; r++) {
          int row = m0 + wr * 64 + i * 16 + fq * 4 + r;
          float c = acc[i][nj][r] + bs + resid[(size_t)row * N + col];
          reinterpret_cast<float*>(outp)[(size_t)row * N + col] = c;
        }
    }
  }
}

// -------- fused sliding-window attention v4 (exp2 + cvt_pk + defer-max) -----
// Scores arrive pre-scaled by log2(e): softmax = 2^(s-m) via raw v_exp_f32.
// Defer-max (THR=8 in log2 domain -> P <= 256, bf16-safe) skips O-rescale.
__global__ __launch_bounds__(256) void attn_fused_kernel(
    const unsigned short* __restrict__ qg, const unsigned short* __restrict__ kg,
    const unsigned short* __restrict__ vtg, const unsigned char* __restrict__ kpm,
    unsigned short* __restrict__ attn_out)
{
  __shared__ unsigned short lds_k[2][64 * 64];
  __shared__ unsigned short lds_vt[2][64 * 64];
  __shared__ unsigned short lds_p[4][32 * 64];
  int bid0 = blockIdx.x;
  int bid = (bid0 & 7) * 96 + (bid0 >> 3);
  int qblk = bid & 31, h = (bid >> 5) % 12, b = bid / 384;
  int bh = b * 12 + h;
  int q0 = qblk * 128;
  int tid = threadIdx.x, w = tid >> 6, l = tid & 63;
  int fr = l & 15, fq = l >> 4;
  int qw0 = q0 + w * 32;
  int swzb = (((l & 7) ^ (l >> 3)) << 4);
  const char* qbase  = (const char*)(qg  + (size_t)bh * 4096 * 64);
  const char* kbase  = (const char*)(kg  + (size_t)bh * 4096 * 64);
  const char* vtbase = (const char*)(vtg + (size_t)bh * 64 * 4096);
  const unsigned char* kpmb = kpm + (size_t)b * 4096;

  #pragma unroll
  for (int s = 0; s < 4; s++) {
    int row = w * 32 + s * 8 + (l >> 3);
    gload16(qbase + (size_t)(q0 + row) * 128 + swzb, (char*)lds_p[w] + s * 1024);
  }

  auto stageKV = [&](int c, int buf) {
    int g0 = q0 - 256 + c * 64;
    if (g0 < 0 || g0 >= 4096) return;
    #pragma unroll
    for (int s = 0; s < 2; s++) {
      int row = w * 16 + s * 8 + (l >> 3);
      gload16(kbase + (size_t)(g0 + row) * 128 + swzb,
              (char*)lds_k[buf] + (w * 2 + s) * 1024);
      gload16(vtbase + ((size_t)row * 4096 + g0) * 2 + swzb,
              (char*)lds_vt[buf] + (w * 2 + s) * 1024);
    }
  };

  stageKV(0, 0);
  asm volatile("s_waitcnt vmcnt(0)");
  __syncthreads();

  short8 qf[2][2];
  #pragma unroll
  for (int i = 0; i < 2; i++)
    #pragma unroll
    for (int ks = 0; ks < 2; ks++)
      qf[i][ks] = *(const short8*)((const char*)lds_p[w] + (i * 16 + fr) * 128 +
                    ((ks * 64 + fq * 16) ^ ((fr & 7) << 4)));

  f32x4 acc_o[2][4] = {};
  float m_st[2] = {-3.0e38f, -3.0e38f};
  float l_st[2] = {0.0f, 0.0f};

  for (int c = 0; c < 10; c++) {
    int g0 = q0 - 256 + c * 64;
    bool valid = (g0 >= 0) && (g0 < 4096);
    if (c < 9) stageKV(c + 1, (c + 1) & 1);
    if (valid) {
      int buf = c & 1;
      unsigned int km[4];
      #pragma unroll
      for (int j = 0; j < 4; j++)
        km[j] = *(const unsigned int*)(kpmb + g0 + 16 * j + 4 * fq);
      bool anyk = __any((km[0] | km[1] | km[2] | km[3]) != 0);
      int rel = g0 - qw0;
      bool edge = anyk || (rel < -225) || (rel > 193);
      short8 kf[4][2];
      #pragma unroll
      for (int j = 0; j < 4; j++)
        #pragma unroll
        for (int ks = 0; ks < 2; ks++)
          kf[j][ks] = *(const short8*)((const char*)lds_k[buf] + (j * 16 + fr) * 128 +
                        ((ks * 64 + fq * 16) ^ ((fr & 7) << 4)));
      f32x4 accs[4][2] = {};
      #pragma unroll
      for (int j = 0; j < 4; j++)
        #pragma unroll
        for (int i = 0; i < 2; i++)
          #pragma unroll
          for (int ks = 0; ks < 2; ks++)
            accs[j][i] = __builtin_amdgcn_mfma_f32_16x16x32_bf16(kf[j][ks], qf[i][ks], accs[j][i], 0, 0, 0);
      #pragma unroll
      for (int i = 0; i < 2; i++) {
        float sv[4][4];
        #pragma unroll
        for (int j = 0; j < 4; j++)
          #pragma unroll
          for (int r = 0; r < 4; r++)
            sv[j][r] = accs[j][i][r];
        if (edge) {
          int base = rel + 4 * fq - fr - 16 * i;
          #pragma unroll
          for (int j = 0; j < 4; j++)
            #pragma unroll
            for (int r = 0; r < 4; r++) {
              int d = base + 16 * j + r;
              bool ok = (d >= -256) && (d <= 256) && (((km[j] >> (8 * r)) & 255u) == 0u);
              if (!ok) sv[j][r] = -1.0e9f;
            }
        }
        float mv = sv[0][0];
        #pragma unroll
        for (int j = 0; j < 4; j++)
          #pragma unroll
          for (int r = 0; r < 4; r++) mv = fmaxf(mv, sv[j][r]);
        mv = fmaxf(mv, __shfl_xor(mv, 16));
        mv = fmaxf(mv, __shfl_xor(mv, 32));
        float mo = m_st[i];
        // T13 defer-max: only rescale when the new chunk-max exceeds m by >8
        if (!__all(mv - mo <= 8.0f)) {
          float mn = fmaxf(mo, mv);
          float scl = exp2v(mo - mn);
          l_st[i] *= scl;
          m_st[i] = mn;
          #pragma unroll
          for (int r = 0; r < 4; r++) {
            float so = __shfl(scl, (l & 48) | ((l >> 2) & 12) | r);
            #pragma unroll
            for (int jd = 0; jd < 4; jd++) acc_o[i][jd][r] *= so;
          }
        }
        float mn = m_st[i];
        float rs = 0.0f;
        char* prow = (char*)lds_p[w] + (i * 16 + fr) * 128;
        #pragma unroll
        for (int j = 0; j < 4; j++) {
          float p0 = exp2v(sv[j][0] - mn), p1 = exp2v(sv[j][1] - mn);
          float p2 = exp2v(sv[j][2] - mn), p3 = exp2v(sv[j][3] - mn);
          rs += (p0 + p1) + (p2 + p3);
          uint2 u; u.x = cvtpk(p0, p1); u.y = cvtpk(p2, p3);
          *(uint2*)(prow + ((32 * j + 8 * fq) ^ ((fr & 7) << 4))) = u;
        }
        rs += __shfl_xor(rs, 16);
        rs += __shfl_xor(rs, 32);
        l_st[i] += rs;
      }
      short8 pf[2][2];
      #pragma unroll
      for (int i = 0; i < 2; i++)
        #pragma unroll
        for (int ks = 0; ks < 2; ks++)
          pf[i][ks] = *(const short8*)((const char*)lds_p[w] + (i * 16 + fr) * 128 +
                        ((ks * 64 + fq * 16) ^ ((fr & 7) << 4)));
      short8 vf[4][2];
      #pragma unroll
      for (int jd = 0; jd < 4; jd++)
        #pragma unroll
        for (int ks = 0; ks < 2; ks++)
          vf[jd][ks] = *(const short8*)((const char*)lds_vt[buf] + (jd * 16 + fr) * 128 +
                        ((ks * 64 + fq * 16) ^ ((fr & 7) << 4)));
      #pragma unroll
      for (int i = 0; i < 2; i++)
        #pragma unroll
        for (int jd = 0; jd < 4; jd++)
          #pragma unroll
          for (int ks = 0; ks < 2; ks++)
            acc_o[i][jd] = __builtin_amdgcn_mfma_f32_16x16x32_bf16(pf[i][ks], vf[jd][ks], acc_o[i][jd], 0, 0, 0);
    }
    asm volatile("s_waitcnt vmcnt(0)");
    __syncthreads();
  }
  #pragma unroll
  for (int i = 0; i < 2; i++) {
    #pragma unroll
    for (int r = 0; r < 4; r++) {
      float lv = __shfl(l_st[i], (l & 48) | ((l >> 2) & 12) | r);
      float inv = 1.0f / lv;
      int qrow = qw0 + i * 16 + fq * 4 + r;
      size_t orow = ((size_t)b * 4096 + qrow) * 768 + h * 64;
      #pragma unroll
      for (int jd = 0; jd < 4; jd++)
        attn_out[orow + jd * 16 + fr] = f2bf(acc_o[i][jd][r] * inv);
    }
  }
}

extern "C" void kernel_launch(void* const* d_in, const int* in_sizes, int n_in,
                              void* d_out, int out_size, void* d_ws, size_t ws_size,
                              hipStream_t stream) {
  const float* x            = (const float*)d_in[0];
  const unsigned char* mask = (const unsigned char*)d_in[1];
  const float* Wq  = (const float*)d_in[3];
  const float* bq  = (const float*)d_in[4];
  const float* Wk  = (const float*)d_in[5];
  const float* bk  = (const float*)d_in[6];
  const float* Wv  = (const float*)d_in[7];
  const float* bv  = (const float*)d_in[8];
  const float* Wo  = (const float*)d_in[9];
  const float* bo  = (const float*)d_in[10];
  const float* ln1g = (const float*)d_in[11];
  const float* ln1b = (const float*)d_in[12];
  const float* W1  = (const float*)d_in[13];
  const float* b1  = (const float*)d_in[14];
  const float* W2  = (const float*)d_in[15];
  const float* b2  = (const float*)d_in[16];
  const float* ln2g = (const float*)d_in[17];
  const float* ln2b = (const float*)d_in[18];
  float* out = (float*)d_out;

  char* ws = (char*)d_ws;
  size_t off = 0;
  auto alloc = [&](size_t bytes) -> void* {
    void* p = ws + off;
    off += (bytes + 255) & ~(size_t)255;
    return p;
  };
  unsigned short* WTqkv = (unsigned short*)alloc((size_t)2304 * 768 * 2);
  unsigned short* WTo   = (unsigned short*)alloc((size_t)768 * 768 * 2);
  unsigned short* W1T   = (unsigned short*)alloc((size_t)3072 * 768 * 2);
  unsigned short* W2T   = (unsigned short*)alloc((size_t)768 * 3072 * 2);
  float*          bqkv  = (float*)alloc(2304 * 4);
  unsigned short* hbuf  = (unsigned short*)alloc((size_t)8192 * 768 * 2);
  unsigned short* qkv   = (unsigned short*)alloc((size_t)3 * 8192 * 768 * 2);
  unsigned short* attn  = (unsigned short*)alloc((size_t)8192 * 768 * 2);
  float* x1             = (float*)alloc((size_t)8192 * 768 * 4);
  unsigned short* h2    = (unsigned short*)alloc((size_t)8192 * 768 * 2);
  unsigned short* a1    = (unsigned short*)alloc((size_t)8192 * 3072 * 2);

  transpose_kernel<<<dim3(24, 24), 256, 0, stream>>>(Wq, WTqkv, 768, 768);
  transpose_kernel<<<dim3(24, 24), 256, 0, stream>>>(Wk, WTqkv + (size_t)768 * 768, 768, 768);
  transpose_kernel<<<dim3(24, 24), 256, 0, stream>>>(Wv, WTqkv + (size_t)1536 * 768, 768, 768);
  transpose_kernel<<<dim3(24, 24), 256, 0, stream>>>(Wo, WTo, 768, 768);
  transpose_kernel<<<dim3(24, 96), 256, 0, stream>>>(W1, W1T, 768, 3072);
  transpose_kernel<<<dim3(96, 24), 256, 0, stream>>>(W2, W2T, 3072, 768);
  catbias_kernel<<<9, 256, 0, stream>>>(bq, bk, bv, bqkv);

  ln_kernel<<<8192, 256, 0, stream>>>(x, ln1g, ln1b, hbuf);

  gemmP_kernel<EPI_QKV><<<576, 512, 0, stream>>>(hbuf, WTqkv, bqkv, nullptr, qkv, 8192, 2304, 768, 9);

  attn_fused_kernel<<<768, 256, 0, stream>>>(qkv, qkv + (size_t)8192 * 768,
                                             qkv + (size_t)2 * 8192 * 768, mask, attn);

  gemmP_kernel<EPI_RESID><<<192, 512, 0, stream>>>(attn, WTo, bo, x, x1, 8192, 768, 768, 3);
  ln_kernel<<<8192, 256, 0, stream>>>(x1, ln2g, ln2b, h2);
  gemmP_kernel<EPI_RELU><<<768, 512, 0, stream>>>(h2, W1T, b1, nullptr, a1, 8192, 3072, 768, 12);
  gemmP_kernel<EPI_RESID><<<192, 512, 0, stream>>>(a1, W2T, b2, x1, out, 8192, 768, 3072, 3);
}

// Round 7
// 259.366 us; speedup vs baseline: 1.9647x; 1.0247x over previous
//
#include <hip/hip_runtime.h>
#include <hip/hip_bf16.h>
#include <cstddef>

typedef __attribute__((ext_vector_type(8))) short short8;
typedef __attribute__((ext_vector_type(4))) float f32x4;
typedef __attribute__((ext_vector_type(4))) unsigned short us4;

typedef __attribute__((address_space(1))) void as1_void;
typedef __attribute__((address_space(3))) void as3_void;

__device__ __forceinline__ void gload16(const void* g, void* lds) {
  __builtin_amdgcn_global_load_lds((as1_void*)(void*)g, (as3_void*)lds, 16, 0, 0);
}

__device__ inline unsigned short f2bf(float f) {
  union { float f; unsigned int u; } v; v.f = f;
  return (unsigned short)((v.u + 0x7FFFu + ((v.u >> 16) & 1u)) >> 16);
}

__device__ __forceinline__ float exp2v(float x) {
  float r; asm("v_exp_f32 %0, %1" : "=v"(r) : "v"(x)); return r;
}
__device__ __forceinline__ unsigned cvtpk(float a, float b) {
  unsigned r; asm("v_cvt_pk_bf16_f32 %0, %1, %2" : "=v"(r) : "v"(a), "v"(b)); return r;
}

// ---------------- LayerNorm: fp32 in -> bf16 out (row = 768) ----------------
__global__ __launch_bounds__(256) void ln_kernel(const float* __restrict__ x,
    const float* __restrict__ g, const float* __restrict__ b,
    unsigned short* __restrict__ out)
{
  int row = blockIdx.x, t = threadIdx.x;
  const float* xr = x + (size_t)row * 768;
  float v0 = xr[t], v1 = xr[t + 256], v2 = xr[t + 512];
  float s = v0 + v1 + v2;
  #pragma unroll
  for (int o = 32; o > 0; o >>= 1) s += __shfl_xor(s, o);
  __shared__ float r1[4], r2[4];
  if ((t & 63) == 0) r1[t >> 6] = s;
  __syncthreads();
  float mean = (r1[0] + r1[1] + r1[2] + r1[3]) * (1.0f / 768.0f);
  float d0 = v0 - mean, d1 = v1 - mean, d2 = v2 - mean;
  float q = d0 * d0 + d1 * d1 + d2 * d2;
  #pragma unroll
  for (int o = 32; o > 0; o >>= 1) q += __shfl_xor(q, o);
  if ((t & 63) == 0) r2[t >> 6] = q;
  __syncthreads();
  float var = (r2[0] + r2[1] + r2[2] + r2[3]) * (1.0f / 768.0f);
  float rs = rsqrtf(var + 1e-6f);
  unsigned short* orow = out + (size_t)row * 768;
  orow[t]       = f2bf(g[t]       * d0 * rs + b[t]);
  orow[t + 256] = f2bf(g[t + 256] * d1 * rs + b[t + 256]);
  orow[t + 512] = f2bf(g[t + 512] * d2 * rs + b[t + 512]);
}

// ------ fused prep: all 6 weight transposes (fp32->bf16) + bias concat ------
__global__ __launch_bounds__(256) void prep_kernel(
    const float* __restrict__ Wq, const float* __restrict__ Wk,
    const float* __restrict__ Wv, const float* __restrict__ Wo,
    const float* __restrict__ W1, const float* __restrict__ W2,
    const float* __restrict__ bq, const float* __restrict__ bk,
    const float* __restrict__ bv,
    unsigned short* __restrict__ WTqkv, unsigned short* __restrict__ WTo,
    unsigned short* __restrict__ W1T, unsigned short* __restrict__ W2T,
    float* __restrict__ bqkv)
{
  int bid = blockIdx.x;
  if (bid >= 6912) {  // 9 blocks of bias concat
    int i = (bid - 6912) * 256 + threadIdx.x;
    bqkv[i] = (i < 768) ? bq[i] : ((i < 1536) ? bk[i - 768] : bv[i - 1536]);
    return;
  }
  const float* W; unsigned short* WT; int K, N, lb;
  if (bid < 576)       { W = Wq; WT = WTqkv;                        K = 768;  N = 768;  lb = bid; }
  else if (bid < 1152) { W = Wk; WT = WTqkv + (size_t)768 * 768;    K = 768;  N = 768;  lb = bid - 576; }
  else if (bid < 1728) { W = Wv; WT = WTqkv + (size_t)1536 * 768;   K = 768;  N = 768;  lb = bid - 1152; }
  else if (bid < 2304) { W = Wo; WT = WTo;                          K = 768;  N = 768;  lb = bid - 1728; }
  else if (bid < 4608) { W = W1; WT = W1T;                          K = 768;  N = 3072; lb = bid - 2304; }
  else                 { W = W2; WT = W2T;                          K = 3072; N = 768;  lb = bid - 4608; }
  int ntN = N >> 5;
  int k0 = (lb / ntN) * 32, n0 = (lb % ntN) * 32;
  __shared__ float tile[32][33];
  int tx = threadIdx.x & 31, ty = threadIdx.x >> 5;
  #pragma unroll
  for (int i = 0; i < 32; i += 8)
    tile[ty + i][tx] = W[(size_t)(k0 + ty + i) * N + n0 + tx];
  __syncthreads();
  #pragma unroll
  for (int i = 0; i < 32; i += 8)
    WT[(size_t)(n0 + ty + i) * K + k0 + tx] = f2bf(tile[tx][ty + i]);
}

enum { EPI_QKV = 0, EPI_RELU = 1, EPI_RESID = 2 };

// ======= 128x256-tile pipelined bf16 GEMM: 8 waves, BK=64, 144KB LDS ========
// 3 LDS buffers, prefetch depth 2. Per half-K-tile phase (m201 sandwich):
// { vmcnt(9); barrier; 12x ds_read_b128; 3x global_load_lds issue; barrier;
//   setprio(1); 16 MFMA; setprio(0) }.  Counted drain 9/6/3/0 in the tail.
template<int EPI>
__global__ __launch_bounds__(512, 1) void gemmP_kernel(
    const unsigned short* __restrict__ A, const unsigned short* __restrict__ BT,
    const float* __restrict__ bias, const float* __restrict__ resid,
    void* __restrict__ outp, int M, int N, int K, int ntn)
{
  __shared__ char lds[3][49152];   // per buf: A [2][8192], B [2][16384]
  int tid = threadIdx.x;
  int nwg = gridDim.x;
  int bid = ((int)blockIdx.x & 7) * (nwg >> 3) + ((int)blockIdx.x >> 3);
  int mt = bid / ntn, nt = bid % ntn;
  int m0 = mt * 128, n0 = nt * 256;
  int w = tid >> 6, l = tid & 63;
  int wr = w >> 2, wc = w & 3;
  int fr = l & 15, fq = l >> 4;
  int swz = (fr >> 1) * 128 + (((((fr & 1) << 2) | fq) ^ ((fr >> 1) & 7)) << 4);
  int t8 = tid >> 3;
  int uu = (tid & 7) ^ (t8 & 7);
  int rb = 2 * t8 + (uu >> 2);
  int kb = (uu & 3) * 8;
  const unsigned short* Asrc  = A  + (size_t)(m0 + rb) * K + kb;
  const unsigned short* Bsrc0 = BT + (size_t)(n0 + rb) * K + kb;
  const unsigned short* Bsrc1 = BT + (size_t)(n0 + 128 + rb) * K + kb;

  auto stage = [&](int buf, int kt, int h) {
    int ko = kt * 64 + h * 32;
    char* dA = &lds[buf][0] + h * 8192 + (w << 10);
    char* dB = &lds[buf][16384] + h * 16384 + (w << 10);
    gload16(Asrc + ko, dA);
    gload16(Bsrc0 + ko, dB);
    gload16(Bsrc1 + ko, dB + 8192);
  };

  f32x4 acc[4][4] = {};
  short8 af[4], bf[4];

#define GP_READ(RBUF, H)                                                       \
  { const char* ab_ = &lds[RBUF][0] + (H) * 8192 + wr * 4096 + swz;            \
    const char* bb_ = &lds[RBUF][16384] + (H) * 16384 + wc * 4096 + swz;       \
    _Pragma("unroll")                                                          \
    for (int i_ = 0; i_ < 4; i_++) af[i_] = *(const short8*)(ab_ + i_ * 1024); \
    _Pragma("unroll")                                                          \
    for (int j_ = 0; j_ < 4; j_++) bf[j_] = *(const short8*)(bb_ + j_ * 1024); }

#define GP_MFMA                                                                \
  __builtin_amdgcn_s_setprio(1);                                               \
  _Pragma("unroll")                                                            \
  for (int i_ = 0; i_ < 4; i_++)                                               \
    _Pragma("unroll")                                                          \
    for (int j_ = 0; j_ < 4; j_++)                                             \
      acc[i_][j_] = __builtin_amdgcn_mfma_f32_16x16x32_bf16(                   \
          af[i_], bf[j_], acc[i_][j_], 0, 0, 0);                               \
  __builtin_amdgcn_s_setprio(0);

#define GP_PHASE(VN, RBUF, H, DOSTAGE, WBUF, KT)                               \
  asm volatile("s_waitcnt vmcnt(" #VN ")" ::: "memory");                       \
  __builtin_amdgcn_s_barrier();                                                \
  GP_READ(RBUF, H);                                                            \
  if (DOSTAGE) stage(WBUF, KT, H);                                             \
  asm volatile("" ::: "memory");                                               \
  __builtin_amdgcn_s_barrier();                                                \
  GP_MFMA;

  // prologue: tiles 0 and 1 fully staged (12 loads in flight)
  stage(0, 0, 0); stage(0, 0, 1); stage(1, 1, 0); stage(1, 1, 1);

  int NT = K >> 6;
  int R = 0;
  for (int t = 0; t < NT - 2; ++t) {
    int W = (R == 0) ? 2 : R - 1;           // (t+2)%3
    GP_PHASE(9, R, 0, 1, W, t + 2);
    GP_PHASE(9, R, 1, 1, W, t + 2);
    R = (R == 2) ? 0 : R + 1;
  }
  // tail: tiles NT-2, NT-1 (no staging; counted drain)
  GP_PHASE(9, R, 0, 0, 0, 0);
  GP_PHASE(6, R, 1, 0, 0, 0);
  R = (R == 2) ? 0 : R + 1;
  GP_PHASE(3, R, 0, 0, 0, 0);
  GP_PHASE(0, R, 1, 0, 0, 0);
#undef GP_PHASE
#undef GP_MFMA
#undef GP_READ

  // epilogue
  #pragma unroll
  for (int nj = 0; nj < 4; nj++) {
    int col = n0 + wc * 64 + nj * 16 + fr;
    float bs = bias[col];
    if (EPI == EPI_QKV) {
      int which = (col >= 1536) ? 2 : ((col >= 768) ? 1 : 0);
      int c2 = col - which * 768;
      int hh = c2 >> 6, dh = c2 & 63;
      if (which == 2) {
        // V^T layout: [b,h,64 d,4096 s]
        unsigned short* dstv = reinterpret_cast<unsigned short*>(outp) + (size_t)2 * 8192 * 768;
        #pragma unroll
        for (int i = 0; i < 4; i++) {
          int row0 = m0 + wr * 64 + i * 16 + fq * 4;
          int bb = row0 >> 12, sl = row0 & 4095;
          us4 pv;
          #pragma unroll
          for (int r = 0; r < 4; r++) pv[r] = f2bf(acc[i][nj][r] + bs);
          *reinterpret_cast<us4*>(&dstv[((size_t)(bb * 12 + hh) * 64 + dh) * 4096 + sl]) = pv;
        }
      } else {
        unsigned short* dst = reinterpret_cast<unsigned short*>(outp) + (size_t)which * 8192 * 768;
        #pragma unroll
        for (int i = 0; i < 4; i++) {
          #pragma unroll
          for (int r = 0; r < 4; r++) {
            int row = m0 + wr * 64 + i * 16 + fq * 4 + r;
            float c = acc[i][nj][r] + bs;
            if (which == 0) c *= 0.18033688011112042f;  // 0.125 * log2(e)
            int bb = row >> 12, sl = row & 4095;
            dst[(((size_t)(bb * 12 + hh)) * 4096 + sl) * 64 + dh] = f2bf(c);
          }
        }
      }
    } else if (EPI == EPI_RELU) {
      #pragma unroll
      for (int i = 0; i < 4; i++)
        #pragma unroll
        for (int r = 0; r < 4; r++) {
          int row = m0 + wr * 64 + i * 16 + fq * 4 + r;
          float c = fmaxf(acc[i][nj][r] + bs, 0.0f);
          reinterpret_cast<unsigned short*>(outp)[(size_t)row * N + col] = f2bf(c);
        }
    } else {
      #pragma unroll
      for (int i = 0; i < 4; i++)
        #pragma unroll
        for (int r = 0; r < 4; r++) {
          int row = m0 + wr * 64 + i * 16 + fq * 4 + r;
          float c = acc[i][nj][r] + bs + resid[(size_t)row * N + col];
          reinterpret_cast<float*>(outp)[(size_t)row * N + col] = c;
        }
    }
  }
}

// -------- fused sliding-window attention v5 (3-buf KV, counted vmcnt) -------
__global__ __launch_bounds__(256) void attn_fused_kernel(
    const unsigned short* __restrict__ qg, const unsigned short* __restrict__ kg,
    const unsigned short* __restrict__ vtg, const unsigned char* __restrict__ kpm,
    unsigned short* __restrict__ attn_out)
{
  __shared__ unsigned short lds_k[3][64 * 64];    // 24 KB
  __shared__ unsigned short lds_vt[3][64 * 64];   // 24 KB
  __shared__ unsigned short lds_p[4][32 * 64];    // 16 KB
  int bid0 = blockIdx.x;
  int bid = (bid0 & 7) * 96 + (bid0 >> 3);
  int qblk = bid & 31, h = (bid >> 5) % 12, b = bid / 384;
  int bh = b * 12 + h;
  int q0 = qblk * 128;
  int tid = threadIdx.x, w = tid >> 6, l = tid & 63;
  int fr = l & 15, fq = l >> 4;
  int qw0 = q0 + w * 32;
  int swzb = (((l & 7) ^ (l >> 3)) << 4);
  const char* qbase  = (const char*)(qg  + (size_t)bh * 4096 * 64);
  const char* kbase  = (const char*)(kg  + (size_t)bh * 4096 * 64);
  const char* vtbase = (const char*)(vtg + (size_t)bh * 64 * 4096);
  const unsigned char* kpmb = kpm + (size_t)b * 4096;

  // Q into per-wave region of lds_p (own-wave loads: vmcnt suffices, no barrier)
  #pragma unroll
  for (int s = 0; s < 4; s++) {
    int row = w * 32 + s * 8 + (l >> 3);
    gload16(qbase + (size_t)(q0 + row) * 128 + swzb, (char*)lds_p[w] + s * 1024);
  }

  auto stageKV = [&](int c, int buf) {
    int g0 = q0 - 256 + c * 64;
    if (g0 < 0 || g0 >= 4096) return;   // only called for staged-valid chunks
    #pragma unroll
    for (int s = 0; s < 2; s++) {
      int row = w * 16 + s * 8 + (l >> 3);
      gload16(kbase + (size_t)(g0 + row) * 128 + swzb,
              (char*)lds_k[buf] + (w * 2 + s) * 1024);
      gload16(vtbase + ((size_t)row * 4096 + g0) * 2 + swzb,
              (char*)lds_vt[buf] + (w * 2 + s) * 1024);
    }
  };
  // uniform-count staging: clamp g0 so every stage issues exactly 4 loads
  auto stageKVc = [&](int c, int buf) {
    int g0 = q0 - 256 + c * 64;
    g0 = (g0 < 0) ? 0 : ((g0 > 4032) ? 4032 : g0);
    #pragma unroll
    for (int s = 0; s < 2; s++) {
      int row = w * 16 + s * 8 + (l >> 3);
      gload16(kbase + (size_t)(g0 + row) * 128 + swzb,
              (char*)lds_k[buf] + (w * 2 + s) * 1024);
      gload16(vtbase + ((size_t)row * 4096 + g0) * 2 + swzb,
              (char*)lds_vt[buf] + (w * 2 + s) * 1024);
    }
  };
  (void)stageKV;

  stageKVc(0, 0);
  stageKVc(1, 1);
  asm volatile("s_waitcnt vmcnt(8)" ::: "memory");   // Q landed (own-wave)

  short8 qf[2][2];
  #pragma unroll
  for (int i = 0; i < 2; i++)
    #pragma unroll
    for (int ks = 0; ks < 2; ks++)
      qf[i][ks] = *(const short8*)((const char*)lds_p[w] + (i * 16 + fr) * 128 +
                    ((ks * 64 + fq * 16) ^ ((fr & 7) << 4)));

  f32x4 acc_o[2][4] = {};
  float m_st[2] = {-3.0e38f, -3.0e38f};
  float l_st[2] = {0.0f, 0.0f};

  for (int c = 0; c < 10; c++) {
    if (c < 9) { asm volatile("s_waitcnt vmcnt(4)" ::: "memory"); }
    else       { asm volatile("s_waitcnt vmcnt(0)" ::: "memory"); }
    __builtin_amdgcn_s_barrier();
    if (c < 8) stageKVc(c + 2, (c + 2) % 3);
    int g0 = q0 - 256 + c * 64;
    bool valid = (g0 >= 0) && (g0 < 4096);
    if (valid) {
      int buf = c % 3;
      unsigned int km[4];
      #pragma unroll
      for (int j = 0; j < 4; j++)
        km[j] = *(const unsigned int*)(kpmb + g0 + 16 * j + 4 * fq);
      bool anyk = __any((km[0] | km[1] | km[2] | km[3]) != 0);
      int rel = g0 - qw0;
      bool edge = anyk || (rel < -225) || (rel > 193);
      short8 kf[4][2];
      #pragma unroll
      for (int j = 0; j < 4; j++)
        #pragma unroll
        for (int ks = 0; ks < 2; ks++)
          kf[j][ks] = *(const short8*)((const char*)lds_k[buf] + (j * 16 + fr) * 128 +
                        ((ks * 64 + fq * 16) ^ ((fr & 7) << 4)));
      f32x4 accs[4][2] = {};
      #pragma unroll
      for (int j = 0; j < 4; j++)
        #pragma unroll
        for (int i = 0; i < 2; i++)
          #pragma unroll
          for (int ks = 0; ks < 2; ks++)
            accs[j][i] = __builtin_amdgcn_mfma_f32_16x16x32_bf16(kf[j][ks], qf[i][ks], accs[j][i], 0, 0, 0);
      #pragma unroll
      for (int i = 0; i < 2; i++) {
        float sv[4][4];
        #pragma unroll
        for (int j = 0; j < 4; j++)
          #pragma unroll
          for (int r = 0; r < 4; r++)
            sv[j][r] = accs[j][i][r];
        if (edge) {
          int base = rel + 4 * fq - fr - 16 * i;
          #pragma unroll
          for (int j = 0; j < 4; j++)
            #pragma unroll
            for (int r = 0; r < 4; r++) {
              int d = base + 16 * j + r;
              bool ok = (d >= -256) && (d <= 256) && (((km[j] >> (8 * r)) & 255u) == 0u);
              if (!ok) sv[j][r] = -1.0e9f;
            }
        }
        float mv = sv[0][0];
        #pragma unroll
        for (int j = 0; j < 4; j++)
          #pragma unroll
          for (int r = 0; r < 4; r++) mv = fmaxf(mv, sv[j][r]);
        mv = fmaxf(mv, __shfl_xor(mv, 16));
        mv = fmaxf(mv, __shfl_xor(mv, 32));
        float mo = m_st[i];
        if (!__all(mv - mo <= 8.0f)) {
          float mn = fmaxf(mo, mv);
          float scl = exp2v(mo - mn);
          l_st[i] *= scl;
          m_st[i] = mn;
          #pragma unroll
          for (int r = 0; r < 4; r++) {
            float so = __shfl(scl, (l & 48) | ((l >> 2) & 12) | r);
            #pragma unroll
            for (int jd = 0; jd < 4; jd++) acc_o[i][jd][r] *= so;
          }
        }
        float mn = m_st[i];
        float rs = 0.0f;
        char* prow = (char*)lds_p[w] + (i * 16 + fr) * 128;
        #pragma unroll
        for (int j = 0; j < 4; j++) {
          float p0 = exp2v(sv[j][0] - mn), p1 = exp2v(sv[j][1] - mn);
          float p2 = exp2v(sv[j][2] - mn), p3 = exp2v(sv[j][3] - mn);
          rs += (p0 + p1) + (p2 + p3);
          uint2 u; u.x = cvtpk(p0, p1); u.y = cvtpk(p2, p3);
          *(uint2*)(prow + ((32 * j + 8 * fq) ^ ((fr & 7) << 4))) = u;
        }
        rs += __shfl_xor(rs, 16);
        rs += __shfl_xor(rs, 32);
        l_st[i] += rs;
      }
      short8 pf[2][2];
      #pragma unroll
      for (int i = 0; i < 2; i++)
        #pragma unroll
        for (int ks = 0; ks < 2; ks++)
          pf[i][ks] = *(const short8*)((const char*)lds_p[w] + (i * 16 + fr) * 128 +
                        ((ks * 64 + fq * 16) ^ ((fr & 7) << 4)));
      short8 vf[4][2];
      #pragma unroll
      for (int jd = 0; jd < 4; jd++)
        #pragma unroll
        for (int ks = 0; ks < 2; ks++)
          vf[jd][ks] = *(const short8*)((const char*)lds_vt[buf] + (jd * 16 + fr) * 128 +
                        ((ks * 64 + fq * 16) ^ ((fr & 7) << 4)));
      #pragma unroll
      for (int i = 0; i < 2; i++)
        #pragma unroll
        for (int jd = 0; jd < 4; jd++)
          #pragma unroll
          for (int ks = 0; ks < 2; ks++)
            acc_o[i][jd] = __builtin_amdgcn_mfma_f32_16x16x32_bf16(pf[i][ks], vf[jd][ks], acc_o[i][jd], 0, 0, 0);
    }
  }
  #pragma unroll
  for (int i = 0; i < 2; i++) {
    #pragma unroll
    for (int r = 0; r < 4; r++) {
      float lv = __shfl(l_st[i], (l & 48) | ((l >> 2) & 12) | r);
      float inv = 1.0f / lv;
      int qrow = qw0 + i * 16 + fq * 4 + r;
      size_t orow = ((size_t)b * 4096 + qrow) * 768 + h * 64;
      #pragma unroll
      for (int jd = 0; jd < 4; jd++)
        attn_out[orow + jd * 16 + fr] = f2bf(acc_o[i][jd][r] * inv);
    }
  }
}

extern "C" void kernel_launch(void* const* d_in, const int* in_sizes, int n_in,
                              void* d_out, int out_size, void* d_ws, size_t ws_size,
                              hipStream_t stream) {
  const float* x            = (const float*)d_in[0];
  const unsigned char* mask = (const unsigned char*)d_in[1];
  const float* Wq  = (const float*)d_in[3];
  const float* bq  = (const float*)d_in[4];
  const float* Wk  = (const float*)d_in[5];
  const float* bk  = (const float*)d_in[6];
  const float* Wv  = (const float*)d_in[7];
  const float* bv  = (const float*)d_in[8];
  const float* Wo  = (const float*)d_in[9];
  const float* bo  = (const float*)d_in[10];
  const float* ln1g = (const float*)d_in[11];
  const float* ln1b = (const float*)d_in[12];
  const float* W1  = (const float*)d_in[13];
  const float* b1  = (const float*)d_in[14];
  const float* W2  = (const float*)d_in[15];
  const float* b2  = (const float*)d_in[16];
  const float* ln2g = (const float*)d_in[17];
  const float* ln2b = (const float*)d_in[18];
  float* out = (float*)d_out;

  char* ws = (char*)d_ws;
  size_t off = 0;
  auto alloc = [&](size_t bytes) -> void* {
    void* p = ws + off;
    off += (bytes + 255) & ~(size_t)255;
    return p;
  };
  unsigned short* WTqkv = (unsigned short*)alloc((size_t)2304 * 768 * 2);
  unsigned short* WTo   = (unsigned short*)alloc((size_t)768 * 768 * 2);
  unsigned short* W1T   = (unsigned short*)alloc((size_t)3072 * 768 * 2);
  unsigned short* W2T   = (unsigned short*)alloc((size_t)768 * 3072 * 2);
  float*          bqkv  = (float*)alloc(2304 * 4);
  unsigned short* hbuf  = (unsigned short*)alloc((size_t)8192 * 768 * 2);
  unsigned short* qkv   = (unsigned short*)alloc((size_t)3 * 8192 * 768 * 2);
  unsigned short* attn  = (unsigned short*)alloc((size_t)8192 * 768 * 2);
  float* x1             = (float*)alloc((size_t)8192 * 768 * 4);
  unsigned short* h2    = (unsigned short*)alloc((size_t)8192 * 768 * 2);
  unsigned short* a1    = (unsigned short*)alloc((size_t)8192 * 3072 * 2);

  prep_kernel<<<6921, 256, 0, stream>>>(Wq, Wk, Wv, Wo, W1, W2, bq, bk, bv,
                                        WTqkv, WTo, W1T, W2T, bqkv);

  ln_kernel<<<8192, 256, 0, stream>>>(x, ln1g, ln1b, hbuf);

  gemmP_kernel<EPI_QKV><<<576, 512, 0, stream>>>(hbuf, WTqkv, bqkv, nullptr, qkv, 8192, 2304, 768, 9);

  attn_fused_kernel<<<768, 256, 0, stream>>>(qkv, qkv + (size_t)8192 * 768,
                                             qkv + (size_t)2 * 8192 * 768, mask, attn);

  gemmP_kernel<EPI_RESID><<<192, 512, 0, stream>>>(attn, WTo, bo, x, x1, 8192, 768, 768, 3);
  ln_kernel<<<8192, 256, 0, stream>>>(x1, ln2g, ln2b, h2);
  gemmP_kernel<EPI_RELU><<<768, 512, 0, stream>>>(h2, W1T, b1, nullptr, a1, 8192, 3072, 768, 12);
  gemmP_kernel<EPI_RESID><<<192, 512, 0, stream>>>(a1, W2T, b2, x1, out, 8192, 768, 3072, 3);
}

// Round 8
// 244.130 us; speedup vs baseline: 2.0873x; 1.0624x over previous
//
#include <hip/hip_runtime.h>
#include <hip/hip_bf16.h>
#include <cstddef>

typedef __attribute__((ext_vector_type(8))) short short8;
typedef __attribute__((ext_vector_type(4))) float f32x4;
typedef __attribute__((ext_vector_type(4))) unsigned short us4;

typedef __attribute__((address_space(1))) void as1_void;
typedef __attribute__((address_space(3))) void as3_void;

__device__ __forceinline__ void gload16(const void* g, void* lds) {
  __builtin_amdgcn_global_load_lds((as1_void*)(void*)g, (as3_void*)lds, 16, 0, 0);
}

__device__ inline unsigned short f2bf(float f) {
  union { float f; unsigned int u; } v; v.f = f;
  return (unsigned short)((v.u + 0x7FFFu + ((v.u >> 16) & 1u)) >> 16);
}

__device__ __forceinline__ float exp2v(float x) {
  float r; asm("v_exp_f32 %0, %1" : "=v"(r) : "v"(x)); return r;
}
__device__ __forceinline__ unsigned cvtpk(float a, float b) {
  unsigned r; asm("v_cvt_pk_bf16_f32 %0, %1, %2" : "=v"(r) : "v"(a), "v"(b)); return r;
}

// ---------------- LayerNorm: fp32 in -> bf16 out (row = 768) ----------------
__global__ __launch_bounds__(256) void ln_kernel(const float* __restrict__ x,
    const float* __restrict__ g, const float* __restrict__ b,
    unsigned short* __restrict__ out)
{
  int row = blockIdx.x, t = threadIdx.x;
  const float* xr = x + (size_t)row * 768;
  float v0 = xr[t], v1 = xr[t + 256], v2 = xr[t + 512];
  float s = v0 + v1 + v2;
  #pragma unroll
  for (int o = 32; o > 0; o >>= 1) s += __shfl_xor(s, o);
  __shared__ float r1[4], r2[4];
  if ((t & 63) == 0) r1[t >> 6] = s;
  __syncthreads();
  float mean = (r1[0] + r1[1] + r1[2] + r1[3]) * (1.0f / 768.0f);
  float d0 = v0 - mean, d1 = v1 - mean, d2 = v2 - mean;
  float q = d0 * d0 + d1 * d1 + d2 * d2;
  #pragma unroll
  for (int o = 32; o > 0; o >>= 1) q += __shfl_xor(q, o);
  if ((t & 63) == 0) r2[t >> 6] = q;
  __syncthreads();
  float var = (r2[0] + r2[1] + r2[2] + r2[3]) * (1.0f / 768.0f);
  float rs = rsqrtf(var + 1e-6f);
  unsigned short* orow = out + (size_t)row * 768;
  orow[t]       = f2bf(g[t]       * d0 * rs + b[t]);
  orow[t + 256] = f2bf(g[t + 256] * d1 * rs + b[t + 256]);
  orow[t + 512] = f2bf(g[t + 512] * d2 * rs + b[t + 512]);
}

// ---- fused prep: 6 weight transposes + bias concat + LN1 (independent) -----
__global__ __launch_bounds__(256) void prep_kernel(
    const float* __restrict__ Wq, const float* __restrict__ Wk,
    const float* __restrict__ Wv, const float* __restrict__ Wo,
    const float* __restrict__ W1, const float* __restrict__ W2,
    const float* __restrict__ bq, const float* __restrict__ bk,
    const float* __restrict__ bv,
    unsigned short* __restrict__ WTqkv, unsigned short* __restrict__ WTo,
    unsigned short* __restrict__ W1T, unsigned short* __restrict__ W2T,
    float* __restrict__ bqkv,
    const float* __restrict__ x, const float* __restrict__ ln1g,
    const float* __restrict__ ln1b, unsigned short* __restrict__ hbuf)
{
  int bid = blockIdx.x;
  int t = threadIdx.x;
  if (bid >= 6921) {  // LN1 rows
    int row = bid - 6921;
    const float* xr = x + (size_t)row * 768;
    float v0 = xr[t], v1 = xr[t + 256], v2 = xr[t + 512];
    float s = v0 + v1 + v2;
    #pragma unroll
    for (int o = 32; o > 0; o >>= 1) s += __shfl_xor(s, o);
    __shared__ float r1[4], r2[4];
    if ((t & 63) == 0) r1[t >> 6] = s;
    __syncthreads();
    float mean = (r1[0] + r1[1] + r1[2] + r1[3]) * (1.0f / 768.0f);
    float d0 = v0 - mean, d1 = v1 - mean, d2 = v2 - mean;
    float q = d0 * d0 + d1 * d1 + d2 * d2;
    #pragma unroll
    for (int o = 32; o > 0; o >>= 1) q += __shfl_xor(q, o);
    if ((t & 63) == 0) r2[t >> 6] = q;
    __syncthreads();
    float var = (r2[0] + r2[1] + r2[2] + r2[3]) * (1.0f / 768.0f);
    float rs = rsqrtf(var + 1e-6f);
    unsigned short* orow = hbuf + (size_t)row * 768;
    orow[t]       = f2bf(ln1g[t]       * d0 * rs + ln1b[t]);
    orow[t + 256] = f2bf(ln1g[t + 256] * d1 * rs + ln1b[t + 256]);
    orow[t + 512] = f2bf(ln1g[t + 512] * d2 * rs + ln1b[t + 512]);
    return;
  }
  if (bid >= 6912) {  // bias concat
    int i = (bid - 6912) * 256 + t;
    bqkv[i] = (i < 768) ? bq[i] : ((i < 1536) ? bk[i - 768] : bv[i - 1536]);
    return;
  }
  const float* W; unsigned short* WT; int K, N, lb;
  if (bid < 576)       { W = Wq; WT = WTqkv;                        K = 768;  N = 768;  lb = bid; }
  else if (bid < 1152) { W = Wk; WT = WTqkv + (size_t)768 * 768;    K = 768;  N = 768;  lb = bid - 576; }
  else if (bid < 1728) { W = Wv; WT = WTqkv + (size_t)1536 * 768;   K = 768;  N = 768;  lb = bid - 1152; }
  else if (bid < 2304) { W = Wo; WT = WTo;                          K = 768;  N = 768;  lb = bid - 1728; }
  else if (bid < 4608) { W = W1; WT = W1T;                          K = 768;  N = 3072; lb = bid - 2304; }
  else                 { W = W2; WT = W2T;                          K = 3072; N = 768;  lb = bid - 4608; }
  int ntN = N >> 5;
  int k0 = (lb / ntN) * 32, n0 = (lb % ntN) * 32;
  __shared__ float tile[32][33];
  int tx = t & 31, ty = t >> 5;
  #pragma unroll
  for (int i = 0; i < 32; i += 8)
    tile[ty + i][tx] = W[(size_t)(k0 + ty + i) * N + n0 + tx];
  __syncthreads();
  #pragma unroll
  for (int i = 0; i < 32; i += 8)
    WT[(size_t)(n0 + ty + i) * K + k0 + tx] = f2bf(tile[tx][ty + i]);
}

enum { EPI_QKV = 0, EPI_RELU = 1, EPI_RESID = 2 };

// ===== 64x256-tile bf16 GEMM: 4 waves (64x64 each), BK=64, 80KB dbuf ========
// 2 blocks/CU (2x80KB = 160KB exactly) -> cross-block overlap hides the
// vmcnt(0)+barrier drain (m97 mechanism). Swizzle pair as validated: LDS
// layout (row, slot u) holds logical col16 = u ^ (row&7); linear gload dest.
template<int EPI>
__global__ __launch_bounds__(256, 2) void gemmW_kernel(
    const unsigned short* __restrict__ A, const unsigned short* __restrict__ BT,
    const float* __restrict__ bias, const float* __restrict__ resid,
    void* __restrict__ outp, int M, int N, int K, int ntn)
{
  __shared__ char lds[2][40960];   // per buf: A 64x128B, B 256x128B
  int tid = threadIdx.x;
  int nwg = gridDim.x;
  int bid = ((int)blockIdx.x & 7) * (nwg >> 3) + ((int)blockIdx.x >> 3);
  int mt = bid / ntn, nt = bid % ntn;
  int m0 = mt * 64, n0 = nt * 256;
  int w = tid >> 6, l = tid & 63;
  int fr = l & 15, fq = l >> 4;
  int rb = tid >> 3;
  int sw8 = ((tid & 7) ^ (rb & 7)) * 8;    // inverse-swizzled element offset
  const unsigned short* As = A  + (size_t)(m0 + rb) * K + sw8;
  const unsigned short* Bs = BT + (size_t)(n0 + rb) * K + sw8;

  auto stage = [&](int buf, int kt) {
    char* d = &lds[buf][0] + tid * 16;
    #pragma unroll
    for (int c = 0; c < 2; c++)
      gload16(As + (size_t)(c * 32) * K + kt * 64, d + c * 4096);
    #pragma unroll
    for (int c = 0; c < 8; c++)
      gload16(Bs + (size_t)(c * 32) * K + kt * 64, d + 8192 + c * 4096);
  };

  f32x4 acc[4][4] = {};
  stage(0, 0);
  asm volatile("s_waitcnt vmcnt(0)" ::: "memory");
  __syncthreads();

  int NT = K >> 6;
  for (int t = 0; t < NT; ++t) {
    int R = t & 1;
    if (t + 1 < NT) stage(R ^ 1, t + 1);
    #pragma unroll
    for (int h = 0; h < 2; h++) {
      short8 af[4], bf[4];
      const char* base = &lds[R][0];
      int colb = (h * 64 + fq * 16) ^ ((fr & 7) << 4);
      #pragma unroll
      for (int i = 0; i < 4; i++)
        af[i] = *(const short8*)(base + (i * 16 + fr) * 128 + colb);
      #pragma unroll
      for (int j = 0; j < 4; j++)
        bf[j] = *(const short8*)(base + 8192 + (w * 64 + j * 16 + fr) * 128 + colb);
      __builtin_amdgcn_s_setprio(1);
      #pragma unroll
      for (int i = 0; i < 4; i++)
        #pragma unroll
        for (int j = 0; j < 4; j++)
          acc[i][j] = __builtin_amdgcn_mfma_f32_16x16x32_bf16(af[i], bf[j], acc[i][j], 0, 0, 0);
      __builtin_amdgcn_s_setprio(0);
    }
    asm volatile("s_waitcnt vmcnt(0)" ::: "memory");
    __syncthreads();
  }

  // epilogue
  #pragma unroll
  for (int nj = 0; nj < 4; nj++) {
    int col = n0 + w * 64 + nj * 16 + fr;
    float bs = bias[col];
    if (EPI == EPI_QKV) {
      int which = (col >= 1536) ? 2 : ((col >= 768) ? 1 : 0);
      int c2 = col - which * 768;
      int hh = c2 >> 6, dh = c2 & 63;
      if (which == 2) {
        // V^T layout: [b,h,64 d,4096 s]
        unsigned short* dstv = reinterpret_cast<unsigned short*>(outp) + (size_t)2 * 8192 * 768;
        #pragma unroll
        for (int i = 0; i < 4; i++) {
          int row0 = m0 + i * 16 + fq * 4;
          int bb = row0 >> 12, sl = row0 & 4095;
          us4 pv;
          #pragma unroll
          for (int r = 0; r < 4; r++) pv[r] = f2bf(acc[i][nj][r] + bs);
          *reinterpret_cast<us4*>(&dstv[((size_t)(bb * 12 + hh) * 64 + dh) * 4096 + sl]) = pv;
        }
      } else {
        unsigned short* dst = reinterpret_cast<unsigned short*>(outp) + (size_t)which * 8192 * 768;
        #pragma unroll
        for (int i = 0; i < 4; i++) {
          #pragma unroll
          for (int r = 0; r < 4; r++) {
            int row = m0 + i * 16 + fq * 4 + r;
            float c = acc[i][nj][r] + bs;
            if (which == 0) c *= 0.18033688011112042f;  // 0.125 * log2(e)
            int bb = row >> 12, sl = row & 4095;
            dst[(((size_t)(bb * 12 + hh)) * 4096 + sl) * 64 + dh] = f2bf(c);
          }
        }
      }
    } else if (EPI == EPI_RELU) {
      #pragma unroll
      for (int i = 0; i < 4; i++)
        #pragma unroll
        for (int r = 0; r < 4; r++) {
          int row = m0 + i * 16 + fq * 4 + r;
          float c = fmaxf(acc[i][nj][r] + bs, 0.0f);
          reinterpret_cast<unsigned short*>(outp)[(size_t)row * N + col] = f2bf(c);
        }
    } else {
      #pragma unroll
      for (int i = 0; i < 4; i++)
        #pragma unroll
        for (int r = 0; r < 4; r++) {
          int row = m0 + i * 16 + fq * 4 + r;
          float c = acc[i][nj][r] + bs + resid[(size_t)row * N + col];
          reinterpret_cast<float*>(outp)[(size_t)row * N + col] = c;
        }
    }
  }
}

// -------- fused sliding-window attention v5 (3-buf KV, counted vmcnt) -------
__global__ __launch_bounds__(256) void attn_fused_kernel(
    const unsigned short* __restrict__ qg, const unsigned short* __restrict__ kg,
    const unsigned short* __restrict__ vtg, const unsigned char* __restrict__ kpm,
    unsigned short* __restrict__ attn_out)
{
  __shared__ unsigned short lds_k[3][64 * 64];
  __shared__ unsigned short lds_vt[3][64 * 64];
  __shared__ unsigned short lds_p[4][32 * 64];
  int bid0 = blockIdx.x;
  int bid = (bid0 & 7) * 96 + (bid0 >> 3);
  int qblk = bid & 31, h = (bid >> 5) % 12, b = bid / 384;
  int bh = b * 12 + h;
  int q0 = qblk * 128;
  int tid = threadIdx.x, w = tid >> 6, l = tid & 63;
  int fr = l & 15, fq = l >> 4;
  int qw0 = q0 + w * 32;
  int swzb = (((l & 7) ^ (l >> 3)) << 4);
  const char* qbase  = (const char*)(qg  + (size_t)bh * 4096 * 64);
  const char* kbase  = (const char*)(kg  + (size_t)bh * 4096 * 64);
  const char* vtbase = (const char*)(vtg + (size_t)bh * 64 * 4096);
  const unsigned char* kpmb = kpm + (size_t)b * 4096;

  #pragma unroll
  for (int s = 0; s < 4; s++) {
    int row = w * 32 + s * 8 + (l >> 3);
    gload16(qbase + (size_t)(q0 + row) * 128 + swzb, (char*)lds_p[w] + s * 1024);
  }

  auto stageKVc = [&](int c, int buf) {
    int g0 = q0 - 256 + c * 64;
    g0 = (g0 < 0) ? 0 : ((g0 > 4032) ? 4032 : g0);
    #pragma unroll
    for (int s = 0; s < 2; s++) {
      int row = w * 16 + s * 8 + (l >> 3);
      gload16(kbase + (size_t)(g0 + row) * 128 + swzb,
              (char*)lds_k[buf] + (w * 2 + s) * 1024);
      gload16(vtbase + ((size_t)row * 4096 + g0) * 2 + swzb,
              (char*)lds_vt[buf] + (w * 2 + s) * 1024);
    }
  };

  stageKVc(0, 0);
  stageKVc(1, 1);
  asm volatile("s_waitcnt vmcnt(8)" ::: "memory");   // Q landed (own-wave)

  short8 qf[2][2];
  #pragma unroll
  for (int i = 0; i < 2; i++)
    #pragma unroll
    for (int ks = 0; ks < 2; ks++)
      qf[i][ks] = *(const short8*)((const char*)lds_p[w] + (i * 16 + fr) * 128 +
                    ((ks * 64 + fq * 16) ^ ((fr & 7) << 4)));

  f32x4 acc_o[2][4] = {};
  float m_st[2] = {-3.0e38f, -3.0e38f};
  float l_st[2] = {0.0f, 0.0f};

  for (int c = 0; c < 10; c++) {
    if (c < 9) { asm volatile("s_waitcnt vmcnt(4)" ::: "memory"); }
    else       { asm volatile("s_waitcnt vmcnt(0)" ::: "memory"); }
    __builtin_amdgcn_s_barrier();
    if (c < 8) stageKVc(c + 2, (c + 2) % 3);
    int g0 = q0 - 256 + c * 64;
    bool valid = (g0 >= 0) && (g0 < 4096);
    if (valid) {
      int buf = c % 3;
      unsigned int km[4];
      #pragma unroll
      for (int j = 0; j < 4; j++)
        km[j] = *(const unsigned int*)(kpmb + g0 + 16 * j + 4 * fq);
      bool anyk = __any((km[0] | km[1] | km[2] | km[3]) != 0);
      int rel = g0 - qw0;
      bool edge = anyk || (rel < -225) || (rel > 193);
      short8 kf[4][2];
      #pragma unroll
      for (int j = 0; j < 4; j++)
        #pragma unroll
        for (int ks = 0; ks < 2; ks++)
          kf[j][ks] = *(const short8*)((const char*)lds_k[buf] + (j * 16 + fr) * 128 +
                        ((ks * 64 + fq * 16) ^ ((fr & 7) << 4)));
      f32x4 accs[4][2] = {};
      #pragma unroll
      for (int j = 0; j < 4; j++)
        #pragma unroll
        for (int i = 0; i < 2; i++)
          #pragma unroll
          for (int ks = 0; ks < 2; ks++)
            accs[j][i] = __builtin_amdgcn_mfma_f32_16x16x32_bf16(kf[j][ks], qf[i][ks], accs[j][i], 0, 0, 0);
      #pragma unroll
      for (int i = 0; i < 2; i++) {
        float sv[4][4];
        #pragma unroll
        for (int j = 0; j < 4; j++)
          #pragma unroll
          for (int r = 0; r < 4; r++)
            sv[j][r] = accs[j][i][r];
        if (edge) {
          int base = rel + 4 * fq - fr - 16 * i;
          #pragma unroll
          for (int j = 0; j < 4; j++)
            #pragma unroll
            for (int r = 0; r < 4; r++) {
              int d = base + 16 * j + r;
              bool ok = (d >= -256) && (d <= 256) && (((km[j] >> (8 * r)) & 255u) == 0u);
              if (!ok) sv[j][r] = -1.0e9f;
            }
        }
        float mv = sv[0][0];
        #pragma unroll
        for (int j = 0; j < 4; j++)
          #pragma unroll
          for (int r = 0; r < 4; r++) mv = fmaxf(mv, sv[j][r]);
        mv = fmaxf(mv, __shfl_xor(mv, 16));
        mv = fmaxf(mv, __shfl_xor(mv, 32));
        float mo = m_st[i];
        if (!__all(mv - mo <= 8.0f)) {
          float mn = fmaxf(mo, mv);
          float scl = exp2v(mo - mn);
          l_st[i] *= scl;
          m_st[i] = mn;
          #pragma unroll
          for (int r = 0; r < 4; r++) {
            float so = __shfl(scl, (l & 48) | ((l >> 2) & 12) | r);
            #pragma unroll
            for (int jd = 0; jd < 4; jd++) acc_o[i][jd][r] *= so;
          }
        }
        float mn = m_st[i];
        float rs = 0.0f;
        char* prow = (char*)lds_p[w] + (i * 16 + fr) * 128;
        #pragma unroll
        for (int j = 0; j < 4; j++) {
          float p0 = exp2v(sv[j][0] - mn), p1 = exp2v(sv[j][1] - mn);
          float p2 = exp2v(sv[j][2] - mn), p3 = exp2v(sv[j][3] - mn);
          rs += (p0 + p1) + (p2 + p3);
          uint2 u; u.x = cvtpk(p0, p1); u.y = cvtpk(p2, p3);
          *(uint2*)(prow + ((32 * j + 8 * fq) ^ ((fr & 7) << 4))) = u;
        }
        rs += __shfl_xor(rs, 16);
        rs += __shfl_xor(rs, 32);
        l_st[i] += rs;
      }
      short8 pf[2][2];
      #pragma unroll
      for (int i = 0; i < 2; i++)
        #pragma unroll
        for (int ks = 0; ks < 2; ks++)
          pf[i][ks] = *(const short8*)((const char*)lds_p[w] + (i * 16 + fr) * 128 +
                        ((ks * 64 + fq * 16) ^ ((fr & 7) << 4)));
      short8 vf[4][2];
      #pragma unroll
      for (int jd = 0; jd < 4; jd++)
        #pragma unroll
        for (int ks = 0; ks < 2; ks++)
          vf[jd][ks] = *(const short8*)((const char*)lds_vt[buf] + (jd * 16 + fr) * 128 +
                        ((ks * 64 + fq * 16) ^ ((fr & 7) << 4)));
      #pragma unroll
      for (int i = 0; i < 2; i++)
        #pragma unroll
        for (int jd = 0; jd < 4; jd++)
          #pragma unroll
          for (int ks = 0; ks < 2; ks++)
            acc_o[i][jd] = __builtin_amdgcn_mfma_f32_16x16x32_bf16(pf[i][ks], vf[jd][ks], acc_o[i][jd], 0, 0, 0);
    }
  }
  #pragma unroll
  for (int i = 0; i < 2; i++) {
    #pragma unroll
    for (int r = 0; r < 4; r++) {
      float lv = __shfl(l_st[i], (l & 48) | ((l >> 2) & 12) | r);
      float inv = 1.0f / lv;
      int qrow = qw0 + i * 16 + fq * 4 + r;
      size_t orow = ((size_t)b * 4096 + qrow) * 768 + h * 64;
      #pragma unroll
      for (int jd = 0; jd < 4; jd++)
        attn_out[orow + jd * 16 + fr] = f2bf(acc_o[i][jd][r] * inv);
    }
  }
}

extern "C" void kernel_launch(void* const* d_in, const int* in_sizes, int n_in,
                              void* d_out, int out_size, void* d_ws, size_t ws_size,
                              hipStream_t stream) {
  const float* x            = (const float*)d_in[0];
  const unsigned char* mask = (const unsigned char*)d_in[1];
  const float* Wq  = (const float*)d_in[3];
  const float* bq  = (const float*)d_in[4];
  const float* Wk  = (const float*)d_in[5];
  const float* bk  = (const float*)d_in[6];
  const float* Wv  = (const float*)d_in[7];
  const float* bv  = (const float*)d_in[8];
  const float* Wo  = (const float*)d_in[9];
  const float* bo  = (const float*)d_in[10];
  const float* ln1g = (const float*)d_in[11];
  const float* ln1b = (const float*)d_in[12];
  const float* W1  = (const float*)d_in[13];
  const float* b1  = (const float*)d_in[14];
  const float* W2  = (const float*)d_in[15];
  const float* b2  = (const float*)d_in[16];
  const float* ln2g = (const float*)d_in[17];
  const float* ln2b = (const float*)d_in[18];
  float* out = (float*)d_out;

  char* ws = (char*)d_ws;
  size_t off = 0;
  auto alloc = [&](size_t bytes) -> void* {
    void* p = ws + off;
    off += (bytes + 255) & ~(size_t)255;
    return p;
  };
  unsigned short* WTqkv = (unsigned short*)alloc((size_t)2304 * 768 * 2);
  unsigned short* WTo   = (unsigned short*)alloc((size_t)768 * 768 * 2);
  unsigned short* W1T   = (unsigned short*)alloc((size_t)3072 * 768 * 2);
  unsigned short* W2T   = (unsigned short*)alloc((size_t)768 * 3072 * 2);
  float*          bqkv  = (float*)alloc(2304 * 4);
  unsigned short* hbuf  = (unsigned short*)alloc((size_t)8192 * 768 * 2);
  unsigned short* qkv   = (unsigned short*)alloc((size_t)3 * 8192 * 768 * 2);
  unsigned short* attn  = (unsigned short*)alloc((size_t)8192 * 768 * 2);
  float* x1             = (float*)alloc((size_t)8192 * 768 * 4);
  unsigned short* h2    = (unsigned short*)alloc((size_t)8192 * 768 * 2);
  unsigned short* a1    = (unsigned short*)alloc((size_t)8192 * 3072 * 2);

  prep_kernel<<<15113, 256, 0, stream>>>(Wq, Wk, Wv, Wo, W1, W2, bq, bk, bv,
                                         WTqkv, WTo, W1T, W2T, bqkv,
                                         x, ln1g, ln1b, hbuf);

  gemmW_kernel<EPI_QKV><<<1152, 256, 0, stream>>>(hbuf, WTqkv, bqkv, nullptr, qkv, 8192, 2304, 768, 9);

  attn_fused_kernel<<<768, 256, 0, stream>>>(qkv, qkv + (size_t)8192 * 768,
                                             qkv + (size_t)2 * 8192 * 768, mask, attn);

  gemmW_kernel<EPI_RESID><<<384, 256, 0, stream>>>(attn, WTo, bo, x, x1, 8192, 768, 768, 3);
  ln_kernel<<<8192, 256, 0, stream>>>(x1, ln2g, ln2b, h2);
  gemmW_kernel<EPI_RELU><<<1536, 256, 0, stream>>>(h2, W1T, b1, nullptr, a1, 8192, 3072, 768, 12);
  gemmW_kernel<EPI_RESID><<<384, 256, 0, stream>>>(a1, W2T, b2, x1, out, 8192, 768, 3072, 3);
}